// Round 11
// baseline (540.500 us; speedup 1.0000x reference)
//
#include <hip/hip_runtime.h>

#define NG 6
#define NN 6000
#define NE 96000
#define NP2 6144   // 24*256, padded rows per graph for k_pair

typedef unsigned int uint;
typedef unsigned short ushort;
typedef unsigned char uchar;
typedef __attribute__((ext_vector_type(8))) short short8;
typedef __attribute__((ext_vector_type(8))) int int8v;
typedef __attribute__((ext_vector_type(4))) float f32x4;
typedef __attribute__((ext_vector_type(2))) float f32x2;

__device__ __forceinline__ ushort f2bf(float f){
  uint u = __float_as_uint(f);
  u = (u + 0x7fffu + ((u >> 16) & 1u)) >> 16;
  return (ushort)u;
}
__device__ __forceinline__ float bf2f(uint u){ return __uint_as_float(u << 16); }

__device__ __forceinline__ void async16(const void* g, void* l){
  __builtin_amdgcn_global_load_lds(
      (const __attribute__((address_space(1))) unsigned int*)g,
      (__attribute__((address_space(3))) unsigned int*)l, 16, 0, 0);
}

__device__ __constant__ int c_i1[21] = {0,0,0,0,0,0,1,1,1,1,1,2,2,2,2,3,3,3,4,4,5};
__device__ __constant__ int c_i2[21] = {0,1,2,3,4,5,1,2,3,4,5,2,3,4,5,3,4,5,4,5,5};
// non-diag pair ids (15) and diag pair ids (6)
__device__ __constant__ int c_nd[15] = {1,2,3,4,5,7,8,9,10,12,13,14,16,17,19};
__device__ __constant__ int c_dg[6]  = {0,6,11,15,18,20};
// cumulative chunk counts per diag row-tile rt=0..23, chunk=16 col-tiles
__device__ __constant__ int c_dcum[25] = {0,6,12,18,24,29,34,39,44,48,52,56,60,
                                          63,66,69,72,74,76,78,80,81,82,83,84};

// ---------------- MFMA tile helpers (XOR-swizzled LDS, bf16 GEMMs) ----------------
// LDS row r (256B): chunk c at slot c^(r&15).
__device__ __forceinline__ void stage128s(const ushort* __restrict__ gsrc, int stride,
                                          ushort* lds, int w, int lane){
  #pragma unroll
  for (int i = 0; i < 8; i++){
    int off = (w*8 + i) * 512;
    int rowi = (w*8 + i)*4 + (lane >> 4);
    int chunk = (lane & 15) ^ (rowi & 15);
    async16(gsrc + (size_t)rowi*stride + chunk*8, (void*)&lds[off]);
  }
}

// stage a 64-row x 128-byte fp8 tile (8KB): row r (128B = 8 slots of 16B),
// source chunk (slot^(r&7)) lands in slot -> read with same XOR is identity.
__device__ __forceinline__ void stage8(const uchar* __restrict__ gsrc,
                                       uchar* lds, int w, int lane){
  #pragma unroll
  for (int j = 0; j < 2; j++){
    int cj = w*2 + j;
    int d = cj*64 + lane;           // 16B-chunk index 0..511
    int row = d >> 3, slot = d & 7;
    async16(gsrc + (size_t)row*128 + ((slot ^ (row & 7)) << 4),
            (void*)(lds + cj*1024));
  }
}

__device__ __forceinline__ void mfma128(const ushort* As, const ushort* Bs,
                                        int w, int lane, f32x4 acc[4][4]){
  int q = lane >> 4, cl = lane & 15;
  int wm = w >> 1, wn = w & 1;
  #pragma unroll
  for (int ks = 0; ks < 4; ks++){
    short8 af[4], bfr[4];
    int ch = ((ks*4 + q) ^ cl) * 8;
    #pragma unroll
    for (int m = 0; m < 4; m++) af[m]  = *(const short8*)&As[(wm*64 + m*16 + cl)*128 + ch];
    #pragma unroll
    for (int n = 0; n < 4; n++) bfr[n] = *(const short8*)&Bs[(wn*64 + n*16 + cl)*128 + ch];
    #pragma unroll
    for (int m = 0; m < 4; m++)
      #pragma unroll
      for (int n = 0; n < 4; n++)
        acc[m][n] = __builtin_amdgcn_mfma_f32_16x16x32_bf16(af[m], bfr[n], acc[m][n], 0, 0, 0);
  }
}
__device__ __forceinline__ void zacc(f32x4 acc[4][4]){
  #pragma unroll
  for (int m = 0; m < 4; m++)
    #pragma unroll
    for (int n = 0; n < 4; n++) acc[m][n] = (f32x4){0.f,0.f,0.f,0.f};
}

// odd deg-9 poly: P(d) ~ 10.5*tanh(d) on [-1,1]  (scalar f32x2 ops — R6-proven;
// v_pk_* inline asm REGRESSED in R9: packed fp32 = 2 FLOP/lane but 2x cycles.)
#define TC1 10.499108f
#define TC3 (-3.4888668f)
#define TC5 1.3464888f
#define TC7 (-0.4433517f)
#define TC9 0.0833385f
__device__ __forceinline__ f32x2 psumT(const f32x4 acc[4][4]){
  f32x2 t2 = {0.f, 0.f};
  #pragma unroll
  for (int m = 0; m < 4; m++)
    #pragma unroll
    for (int n = 0; n < 4; n++)
      #pragma unroll
      for (int rp = 0; rp < 2; rp++){
        f32x2 d = { acc[m][n][rp*2], acc[m][n][rp*2+1] };
        f32x2 t = d*d;
        f32x2 qq = t*TC9 + TC7;
        qq = qq*t + TC5;
        qq = qq*t + TC3;
        qq = qq*t + TC1;
        t2 = d*qq + t2;
      }
  return t2;
}

// ---------------- tiny utility kernels ----------------
__global__ void k_zero4(float4* p, int n16){
  int i = blockIdx.x*256 + threadIdx.x;
  if (i < n16) p[i] = make_float4(0.f,0.f,0.f,0.f);
}
__global__ void k_zero1(float* p, int n){
  int i = blockIdx.x*256 + threadIdx.x;
  if (i < n) p[i] = 0.f;
}
__global__ void k_cvtx(const float4* x, uint2* xbf, int n4){
  int i = blockIdx.x*256 + threadIdx.x;
  if (i >= n4) return;
  float4 v = x[i];
  xbf[i] = make_uint2((uint)f2bf(v.x) | ((uint)f2bf(v.y) << 16),
                      (uint)f2bf(v.z) | ((uint)f2bf(v.w) << 16));
}
// Wtc[l][c][k] = W[l][k][c];  Wstc[n][l*128+c'] = Ws[l][c'][n]
__global__ void k_cvt_w(const float* W, const float* Wsm, ushort* Wtc, ushort* Wstc){
  int i = blockIdx.x*256 + threadIdx.x;   // 65536
  int l = i >> 14, rem = i & 16383;
  int a = rem >> 7, b = rem & 127;        // W: a=k,b=c ; Ws: a=c',b=n
  Wtc[(l << 14) + b*128 + a] = f2bf(W[i]);
  Wstc[b*512 + l*128 + a]    = f2bf(Wsm[i]);
}
__global__ void k_count(const int* ei, int* counts){
  int i = blockIdx.x*256 + threadIdx.x;
  if (i >= NG*NE) return;
  int g = i / NE, e = i - g*NE;
  atomicAdd(&counts[g*NN + ei[g*2*NE + NE + e]], 1);
}
__global__ void k_scan(const int* counts, int* offs, int* cursor){
  __shared__ int sm[256];
  int g = blockIdx.x, t = threadIdx.x;
  const int* c = counts + g*NN;
  int i0 = t*24, i1 = i0 + 24; if (i1 > NN) i1 = NN; if (i0 > NN) i0 = NN;
  int s = 0;
  for (int i = i0; i < i1; i++) s += c[i];
  sm[t] = s;
  __syncthreads();
  for (int off = 1; off < 256; off <<= 1){
    int v = (t >= off) ? sm[t - off] : 0;
    __syncthreads();
    sm[t] += v;
    __syncthreads();
  }
  int run = sm[t] - s;
  for (int i = i0; i < i1; i++){
    offs[g*NN + i] = run; cursor[g*NN + i] = run; run += c[i];
  }
}
__global__ void k_place(const int* ei, int* cursor, int2* elist2){
  int i = blockIdx.x*256 + threadIdx.x;
  if (i >= NG*NE) return;
  int g = i / NE, e = i - g*NE;
  int col = ei[g*2*NE + NE + e];
  int row = ei[g*2*NE + e];
  int pos = atomicAdd(&cursor[g*NN + col], 1);
  elist2[g*NE + pos] = make_int2(e, row);
}
__global__ void k_deg(const float* __restrict__ ea, const int* __restrict__ offs,
                      const int* __restrict__ counts, const int2* __restrict__ elist2,
                      float4* __restrict__ dis4){
  int i = blockIdx.x*256 + threadIdx.x;
  if (i >= NG*NN) return;
  int g = i / NN;
  int beg = offs[i], cnt = counts[i];
  const int2* el = elist2 + (size_t)g*NE;
  const float* eag = ea + (size_t)g*NE*6;
  float4 s = make_float4(1.f,1.f,1.f,1.f);
  for (int j = 0; j < cnt; j++){
    int e = el[beg + j].x;
    float2 wa = *(const float2*)(eag + (size_t)e*6 + 2);
    float2 wb = *(const float2*)(eag + (size_t)e*6 + 4);
    s.x += wa.x; s.y += wa.y; s.z += wb.x; s.w += wb.y;
  }
  dis4[i] = make_float4(rsqrtf(fmaxf(s.x,1e-30f)), rsqrtf(fmaxf(s.y,1e-30f)),
                        rsqrtf(fmaxf(s.z,1e-30f)), rsqrtf(fmaxf(s.w,1e-30f)));
}

// ---------------- aggregate-first: agg[lg*4+l][n][128] = dn_l*(sum coef*x[r] + dn_l*x[n]) ----------------
__global__ __launch_bounds__(256) void k_gather1(const float* __restrict__ ea,
    const float4* __restrict__ dis4, const int* __restrict__ offs,
    const int* __restrict__ counts, const int2* __restrict__ elist2,
    const ushort* __restrict__ xbf, ushort* __restrict__ agg, int c){
  __shared__ int    sr[4][64];
  __shared__ float4 sc[4][64];
  int lane = threadIdx.x, wy = threadIdx.y;
  int nidx = blockIdx.x*4 + wy;            // 0..11999
  int lg = nidx / NN, n = nidx - lg*NN;
  int g = c*2 + lg;
  float4 dn4 = dis4[g*NN + n];
  const uint* xrow = (const uint*)xbf + (size_t)lg*NN*64;
  uint xv = xrow[(size_t)n*64 + lane];
  f32x2 xs = {bf2f(xv & 0xffffu), bf2f(xv >> 16)};
  f32x2 a0 = xs*dn4.x, a1 = xs*dn4.y, a2 = xs*dn4.z, a3 = xs*dn4.w;
  int beg = offs[g*NN + n], cnt = counts[g*NN + n];
  const int2*  el  = elist2 + (size_t)g*NE;
  const float* eag = ea + (size_t)g*NE*6;
  for (int j0 = 0; j0 < cnt; j0 += 64){
    int take = cnt - j0; if (take > 64) take = 64;
    if (lane < take){
      int2 er = el[beg + j0 + lane];
      float2 wa = *(const float2*)(eag + (size_t)er.x*6 + 2);
      float2 wb = *(const float2*)(eag + (size_t)er.x*6 + 4);
      float4 dr = dis4[g*NN + er.y];
      sr[wy][lane] = er.y;
      sc[wy][lane] = make_float4(wa.x*dr.x, wa.y*dr.y, wb.x*dr.z, wb.y*dr.w);
    }
    int j = 0;
    for (; j + 4 <= take; j += 4){
      int r0 = sr[wy][j], r1 = sr[wy][j+1], r2 = sr[wy][j+2], r3 = sr[wy][j+3];
      float4 c0 = sc[wy][j], c1 = sc[wy][j+1], c2 = sc[wy][j+2], c3 = sc[wy][j+3];
      uint x0 = xrow[(size_t)r0*64 + lane];
      uint x1 = xrow[(size_t)r1*64 + lane];
      uint x2 = xrow[(size_t)r2*64 + lane];
      uint x3 = xrow[(size_t)r3*64 + lane];
      f32x2 v;
      v = (f32x2){bf2f(x0 & 0xffffu), bf2f(x0 >> 16)};
      a0 = v*c0.x + a0; a1 = v*c0.y + a1; a2 = v*c0.z + a2; a3 = v*c0.w + a3;
      v = (f32x2){bf2f(x1 & 0xffffu), bf2f(x1 >> 16)};
      a0 = v*c1.x + a0; a1 = v*c1.y + a1; a2 = v*c1.z + a2; a3 = v*c1.w + a3;
      v = (f32x2){bf2f(x2 & 0xffffu), bf2f(x2 >> 16)};
      a0 = v*c2.x + a0; a1 = v*c2.y + a1; a2 = v*c2.z + a2; a3 = v*c2.w + a3;
      v = (f32x2){bf2f(x3 & 0xffffu), bf2f(x3 >> 16)};
      a0 = v*c3.x + a0; a1 = v*c3.y + a1; a2 = v*c3.z + a2; a3 = v*c3.w + a3;
    }
    for (; j < take; j++){
      int r0 = sr[wy][j];
      float4 c0 = sc[wy][j];
      uint x0 = xrow[(size_t)r0*64 + lane];
      f32x2 v = (f32x2){bf2f(x0 & 0xffffu), bf2f(x0 >> 16)};
      a0 = v*c0.x + a0; a1 = v*c0.y + a1; a2 = v*c0.z + a2; a3 = v*c0.w + a3;
    }
  }
  a0 = a0*dn4.x; a1 = a1*dn4.y; a2 = a2*dn4.z; a3 = a3*dn4.w;
  uint* ag = (uint*)agg;
  ag[((size_t)((lg*4+0)*NN + n))*64 + lane] = (uint)f2bf(a0.x) | ((uint)f2bf(a0.y) << 16);
  ag[((size_t)((lg*4+1)*NN + n))*64 + lane] = (uint)f2bf(a1.x) | ((uint)f2bf(a1.y) << 16);
  ag[((size_t)((lg*4+2)*NN + n))*64 + lane] = (uint)f2bf(a2.x) | ((uint)f2bf(a2.y) << 16);
  ag[((size_t)((lg*4+3)*NN + n))*64 + lane] = (uint)f2bf(a3.x) | ((uint)f2bf(a3.y) << 16);
}

// ---------------- fused GEMM: feats[coff+lg*NN+row][n] = sum_l relu(agg_l@W_l+b_l) @ Ws_l^T ----------------
// Replaces k_gemm1b (H to HBM) + k_gemm2 (H from HBM): H_l lives one l-iteration
// in the As LDS buffer (bf16, XOR-swizzled A layout). Math path bit-identical:
// same MFMAs, same f2bf(relu(acc+b)) rounding, same B staging (Wstc stride 512).
// Rows >= NN: garbage agg only pollutes its own output row (A-row r -> C-row r),
// which is skipped at the feats write; fmaxf(NaN,0)=0 keeps LDS values finite.
__global__ __launch_bounds__(256, 2) void k_gemmf(const ushort* __restrict__ agg,
    const ushort* __restrict__ Wtc, const float* __restrict__ gb,
    const ushort* __restrict__ Wstc, float* __restrict__ feats, int coff){
  __shared__ ushort As[16384];
  __shared__ ushort Bsh[16384];
  int bx = blockIdx.x;            // 47 row-tiles of 128
  int lg = blockIdx.y;            // 0..1
  int tid = threadIdx.x, w = tid >> 6, lane = tid & 63;
  int q = lane >> 4, cl = lane & 15, wm = w >> 1, wn = w & 1;
  int rowb_l = wm*64 + q*4;       // local row base (0..127)
  int colb = wn*64 + cl;
  f32x4 accf[4][4];
  zacc(accf);
  #pragma unroll 1
  for (int l = 0; l < 4; l++){
    if (l) __syncthreads();                       // prev mfma2 reads done
    stage128s(agg + (size_t)(lg*4+l)*NN*128 + (size_t)bx*16384, 128, As, w, lane);
    stage128s(Wtc + (l << 14), 128, Bsh, w, lane);
    __syncthreads();
    f32x4 acc[4][4];
    zacc(acc);
    mfma128(As, Bsh, w, lane, acc);
    __syncthreads();                              // all reads of As/Bsh done
    // H_l = relu(acc + b) -> bf16 into As, XOR-swizzled A layout
    #pragma unroll
    for (int m = 0; m < 4; m++)
      #pragma unroll
      for (int n = 0; n < 4; n++)
        #pragma unroll
        for (int r = 0; r < 4; r++){
          int row = rowb_l + m*16 + r;
          int col = colb + n*16;
          float v = fmaxf(acc[m][n][r] + gb[l*128 + col], 0.f);
          As[row*128 + (((col >> 3) ^ (row & 15)) << 3) + (col & 7)] = f2bf(v);
        }
    stage128s(Wstc + l*128, 512, Bsh, w, lane);   // Ws_l panel (row n, stride 512)
    __syncthreads();                              // H writes + Ws staging done
    mfma128(As, Bsh, w, lane, accf);              // feats += H_l @ Ws_l^T
  }
  #pragma unroll
  for (int m = 0; m < 4; m++)
    #pragma unroll
    for (int n = 0; n < 4; n++)
      #pragma unroll
      for (int r = 0; r < 4; r++){
        int grow = bx*128 + rowb_l + m*16 + r;
        if (grow < NN)
          feats[(size_t)(coff + lg*NN + grow)*128 + colb + n*16] = accf[m][n][r];
      }
}

__global__ void k_mean(const float* feats, float* out){
  int g = blockIdx.x / 48, ch = blockIdx.x - g*48;
  int c = threadIdx.x;
  float s = 0.f;
  int n0 = ch*125;
  for (int n = n0; n < n0 + 125; n++) s += feats[((size_t)(g*NN + n))*128 + c];
  atomicAdd(&out[g*128 + c], s * (1.0f/6000.0f));
}

// normalize rows -> fp8 e4m3, zero-pad to 6144 rows per graph
__global__ void k_xn(const float* feats, uchar* xn8){
  int lane = threadIdx.x;
  int rall = blockIdx.x*4 + threadIdx.y;   // 0..36863
  int g = rall / NP2, rl = rall - g*NP2;
  ushort* dst = (ushort*)(xn8 + ((size_t)(g*NP2 + rl))*128);
  if (rl < NN){
    const float2* src = (const float2*)&feats[((size_t)(g*NN + rl))*128];
    float2 v = src[lane];
    float ss = v.x*v.x + v.y*v.y;
    #pragma unroll
    for (int s = 32; s > 0; s >>= 1) ss += __shfl_xor(ss, s);
    float inv = 1.0f / fmaxf(sqrtf(ss), 1e-12f);
    int pk = __builtin_amdgcn_cvt_pk_fp8_f32(v.x*inv, v.y*inv, 0, false);
    dst[lane] = (ushort)(pk & 0xffff);
  } else {
    dst[lane] = 0;
  }
}

// ---------------- pairwise v11: MX-FP8 K=128, scalar poly, (256,3) ----------------
// Plateau-proven body (148-150us across (256,2)/(256,3)): scalar psumT, single
// bfr[4]+acc[4][4] MFMA region, no spill (WRITE ~333KB).
__global__ __launch_bounds__(256, 3) void k_pair(const uchar* __restrict__ xn8,
                                                 float* Spart){
  __shared__ uchar Bs[2][8192];
  int bx = blockIdx.x;              // 2664 = 15*144 + 6*84
  int p, rt, c0, niter; bool diag;
  if (bx < 2160){
    int pp = bx / 144, rem = bx - pp*144;
    rt = rem / 6; int ch = rem - rt*6;
    p = c_nd[pp]; diag = false; c0 = ch*16; niter = 16;
  } else {
    int idd = bx - 2160;
    int pd = idd / 84, rem = idd - pd*84;
    int r_ = 0;
    while (c_dcum[r_ + 1] <= rem) r_++;
    rt = r_;
    int ch = rem - c_dcum[rt];
    p = c_dg[pd]; diag = true;
    c0 = 4*rt + ch*16;
    int left = 96 - c0;
    niter = left < 16 ? left : 16;
  }
  int i1 = c_i1[p], i2 = c_i2[p];
  int tid = threadIdx.x, w = tid >> 6, lane = tid & 63;
  int q = lane >> 4, cl = lane & 15;
  // A: 64 rows/wave = 4 m-tiles of 16; lane holds row (cl), k-bytes q*32..+32
  const uchar* Arow = xn8 + ((size_t)i1*NP2 + rt*256 + w*64 + cl)*128 + q*32;
  int8v afr[4];
  #pragma unroll
  for (int m = 0; m < 4; m++){
    uint4 lo = *(const uint4*)(Arow + m*2048);
    uint4 hi = *(const uint4*)(Arow + m*2048 + 16);
    afr[m] = (int8v){(int)lo.x,(int)lo.y,(int)lo.z,(int)lo.w,
                     (int)hi.x,(int)hi.y,(int)hi.z,(int)hi.w};
  }
  // LDS read byte-bases (swizzled), loop-invariant:
  int b0 = cl*128 + (((q*2  ) ^ (cl & 7)) << 4);
  int b1 = cl*128 + (((q*2+1) ^ (cl & 7)) << 4);
  const uchar* Bbase = xn8 + (size_t)i2*NP2*128;
  stage8(Bbase + (size_t)c0*8192, Bs[0], w, lane);
  f32x2 totw = {0.f, 0.f};
  const f32x4 z4 = {0.f,0.f,0.f,0.f};
  for (int it = 0; it < niter; it++){
    int cur = it & 1;
    __syncthreads();                               // drains staging of Bs[cur]
    if (it + 1 < niter)
      stage8(Bbase + (size_t)(c0+it+1)*8192, Bs[1-cur], w, lane);
    __builtin_amdgcn_s_setprio(1);
    int8v bfr[4];
    #pragma unroll
    for (int n = 0; n < 4; n++){
      uint4 lo = *(const uint4*)&Bs[cur][b0 + n*2048];
      uint4 hi = *(const uint4*)&Bs[cur][b1 + n*2048];
      bfr[n] = (int8v){(int)lo.x,(int)lo.y,(int)lo.z,(int)lo.w,
                       (int)hi.x,(int)hi.y,(int)hi.z,(int)hi.w};
    }
    f32x4 acc[4][4];
    #pragma unroll
    for (int m = 0; m < 4; m++)
      #pragma unroll
      for (int n = 0; n < 4; n++)
        acc[m][n] = __builtin_amdgcn_mfma_scale_f32_16x16x128_f8f6f4(
            afr[m], bfr[n], z4, 0, 0, 0, 0x7F, 0, 0x7F);
    __builtin_amdgcn_s_setprio(0);
    f32x2 t2 = psumT(acc);
    float wgt = (diag && (c0 + it) >= 4*rt + 4) ? 2.f : 1.f;
    totw = t2*wgt + totw;
  }
  float tot = totw.x + totw.y;
  #pragma unroll
  for (int s = 32; s > 0; s >>= 1) tot += __shfl_xor(tot, s);
  if (lane == 0) atomicAdd(&Spart[p*64 + (bx & 63)], tot);
}

__global__ void k_final(const float* Spart, float* out){
  int t = threadIdx.x;
  if (t < 21){
    float s = 0.f;
    for (int j = 0; j < 64; j++) s += Spart[t*64 + j];
    float v = s * (1.0f/360000000.0f);
    int i1 = c_i1[t], i2 = c_i2[t];
    out[768 + i1*6 + i2] = v;
    out[768 + i2*6 + i1] = v;
  }
}

extern "C" void kernel_launch(void* const* d_in, const int* in_sizes, int n_in,
                              void* d_out, int out_size, void* d_ws, size_t ws_size,
                              hipStream_t stream){
  (void)in_sizes; (void)n_in; (void)out_size; (void)ws_size;
  const float* x   = (const float*)d_in[0];
  const int*   ei  = (const int*)d_in[1];
  const float* ea  = (const float*)d_in[2];
  const float* gW  = (const float*)d_in[3];
  const float* gb  = (const float*)d_in[4];
  const float* Wsm = (const float*)d_in[5];
  float* out = (float*)d_out;
  char* ws = (char*)d_ws;
  // workspace (bytes), peak ~39.7 MiB (H eliminated by k_gemmf fusion)
  float*  feats  = (float*) (ws + 0);           // 18,432,000
  int*    counts = (int*)   (ws + 18432000);    //    144,000
  int*    offs   = (int*)   (ws + 18576000);    //    144,000
  int*    cursor = (int*)   (ws + 18720000);    //    144,000
  float*  Spart  = (float*) (ws + 18864000);    //      8,192   [zero 18,432,000..18,872,192)
  float4* dis4   = (float4*)(ws + 18872192);    //    576,000
  int2*   elist2 = (int2*)  (ws + 19448192);    //  4,608,000
  ushort* Wtc    = (ushort*)(ws + 24056192);    //    131,072
  ushort* Wstc   = (ushort*)(ws + 24187264);    //    131,072
  ushort* xbf    = (ushort*)(ws + 24318336);    //  3,072,000
  ushort* agg    = (ushort*)(ws + 27394560);    // 12,288,000 (+8 KB pad) -> end 39,690,752
  uchar*  xn8    = (uchar*) (ws + 24318336);    //  4,718,592 overlay (xbf/agg dead by k_xn)

  k_zero4<<<dim3(108), dim3(256), 0, stream>>>((float4*)(ws + 18432000), 27512);
  k_zero1<<<dim3(4),   dim3(256), 0, stream>>>(out, 804);
  k_cvt_w<<<dim3(256), dim3(256), 0, stream>>>(gW, Wsm, Wtc, Wstc);
  k_count<<<dim3(2250), dim3(256), 0, stream>>>(ei, counts);
  k_scan <<<dim3(6),    dim3(256), 0, stream>>>(counts, offs, cursor);
  k_place<<<dim3(2250), dim3(256), 0, stream>>>(ei, cursor, elist2);
  k_deg  <<<dim3(141),  dim3(256), 0, stream>>>(ea, offs, counts, elist2, dis4);
  for (int c = 0; c < 3; c++){
    k_cvtx   <<<dim3(1500), dim3(256), 0, stream>>>(
        (const float4*)(x + (size_t)c*2*NN*128), (uint2*)xbf, 384000);
    k_gather1<<<dim3(3000), dim3(64,4), 0, stream>>>(ea, dis4, offs, counts, elist2,
                                                     xbf, agg, c);
    k_gemmf  <<<dim3(47,2), dim3(256), 0, stream>>>(agg, Wtc, gb, Wstc, feats, c*2*NN);
  }
  k_mean <<<dim3(288),  dim3(128),  0, stream>>>(feats, out);
  k_xn   <<<dim3(9216), dim3(64,4), 0, stream>>>(feats, xn8);
  k_pair <<<dim3(2664), dim3(256),  0, stream>>>(xn8, Spart);
  k_final<<<dim3(1),    dim3(64),   0, stream>>>(Spart, out);
}

// Round 12
// 473.238 us; speedup vs baseline: 1.1421x; 1.1421x over previous
//
#include <hip/hip_runtime.h>

#define NG 6
#define NN 6000
#define NE 96000
#define NP2 6144   // 24*256, padded rows per graph for k_pair

typedef unsigned int uint;
typedef unsigned short ushort;
typedef unsigned char uchar;
typedef __attribute__((ext_vector_type(8))) short short8;
typedef __attribute__((ext_vector_type(8))) int int8v;
typedef __attribute__((ext_vector_type(4))) float f32x4;
typedef __attribute__((ext_vector_type(2))) float f32x2;

__device__ __forceinline__ ushort f2bf(float f){
  uint u = __float_as_uint(f);
  u = (u + 0x7fffu + ((u >> 16) & 1u)) >> 16;
  return (ushort)u;
}
__device__ __forceinline__ float bf2f(uint u){ return __uint_as_float(u << 16); }

__device__ __forceinline__ void async16(const void* g, void* l){
  __builtin_amdgcn_global_load_lds(
      (const __attribute__((address_space(1))) unsigned int*)g,
      (__attribute__((address_space(3))) unsigned int*)l, 16, 0, 0);
}

__device__ __constant__ int c_i1[21] = {0,0,0,0,0,0,1,1,1,1,1,2,2,2,2,3,3,3,4,4,5};
__device__ __constant__ int c_i2[21] = {0,1,2,3,4,5,1,2,3,4,5,2,3,4,5,3,4,5,4,5,5};
// non-diag pair ids (15) and diag pair ids (6)
__device__ __constant__ int c_nd[15] = {1,2,3,4,5,7,8,9,10,12,13,14,16,17,19};
__device__ __constant__ int c_dg[6]  = {0,6,11,15,18,20};
// cumulative chunk counts per diag row-tile rt=0..23, chunk=16 col-tiles
__device__ __constant__ int c_dcum[25] = {0,6,12,18,24,29,34,39,44,48,52,56,60,
                                          63,66,69,72,74,76,78,80,81,82,83,84};

// ---------------- MFMA tile helpers (XOR-swizzled LDS, bf16 GEMMs) ----------------
// LDS row r (256B): chunk c at slot c^(r&15).
__device__ __forceinline__ void stage128s(const ushort* __restrict__ gsrc, int stride,
                                          ushort* lds, int w, int lane){
  #pragma unroll
  for (int i = 0; i < 8; i++){
    int off = (w*8 + i) * 512;
    int rowi = (w*8 + i)*4 + (lane >> 4);
    int chunk = (lane & 15) ^ (rowi & 15);
    async16(gsrc + (size_t)rowi*stride + chunk*8, (void*)&lds[off]);
  }
}

// stage a 64-row x 128-byte fp8 tile (8KB): row r (128B = 8 slots of 16B),
// source chunk (slot^(r&7)) lands in slot -> read with same XOR is identity.
__device__ __forceinline__ void stage8(const uchar* __restrict__ gsrc,
                                       uchar* lds, int w, int lane){
  #pragma unroll
  for (int j = 0; j < 2; j++){
    int cj = w*2 + j;
    int d = cj*64 + lane;           // 16B-chunk index 0..511
    int row = d >> 3, slot = d & 7;
    async16(gsrc + (size_t)row*128 + ((slot ^ (row & 7)) << 4),
            (void*)(lds + cj*1024));
  }
}

__device__ __forceinline__ void mfma128(const ushort* As, const ushort* Bs,
                                        int w, int lane, f32x4 acc[4][4]){
  int q = lane >> 4, cl = lane & 15;
  int wm = w >> 1, wn = w & 1;
  #pragma unroll
  for (int ks = 0; ks < 4; ks++){
    short8 af[4], bfr[4];
    int ch = ((ks*4 + q) ^ cl) * 8;
    #pragma unroll
    for (int m = 0; m < 4; m++) af[m]  = *(const short8*)&As[(wm*64 + m*16 + cl)*128 + ch];
    #pragma unroll
    for (int n = 0; n < 4; n++) bfr[n] = *(const short8*)&Bs[(wn*64 + n*16 + cl)*128 + ch];
    #pragma unroll
    for (int m = 0; m < 4; m++)
      #pragma unroll
      for (int n = 0; n < 4; n++)
        acc[m][n] = __builtin_amdgcn_mfma_f32_16x16x32_bf16(af[m], bfr[n], acc[m][n], 0, 0, 0);
  }
}
__device__ __forceinline__ void zacc(f32x4 acc[4][4]){
  #pragma unroll
  for (int m = 0; m < 4; m++)
    #pragma unroll
    for (int n = 0; n < 4; n++) acc[m][n] = (f32x4){0.f,0.f,0.f,0.f};
}

// odd deg-9 poly: P(d) ~ 10.5*tanh(d) on [-1,1]  (scalar f32x2 ops — R6-proven;
// v_pk_* inline asm REGRESSED in R9: packed fp32 = 2 FLOP/lane but 2x cycles.)
#define TC1 10.499108f
#define TC3 (-3.4888668f)
#define TC5 1.3464888f
#define TC7 (-0.4433517f)
#define TC9 0.0833385f
__device__ __forceinline__ f32x2 psumT(const f32x4 acc[4][4]){
  f32x2 t2 = {0.f, 0.f};
  #pragma unroll
  for (int m = 0; m < 4; m++)
    #pragma unroll
    for (int n = 0; n < 4; n++)
      #pragma unroll
      for (int rp = 0; rp < 2; rp++){
        f32x2 d = { acc[m][n][rp*2], acc[m][n][rp*2+1] };
        f32x2 t = d*d;
        f32x2 qq = t*TC9 + TC7;
        qq = qq*t + TC5;
        qq = qq*t + TC3;
        qq = qq*t + TC1;
        t2 = d*qq + t2;
      }
  return t2;
}

// ---------------- init: zero scratch/out + convert weights (3 launches -> 1) ----------------
// Wtc[l][c][k] = W[l][k][c];  Wstc[n][l*128+c'] = Ws[l][c'][n]
__global__ void k_init(const float* W, const float* Wsm, ushort* Wtc, ushort* Wstc,
                       float4* zr, float* out){
  int i = blockIdx.x*256 + threadIdx.x;   // 65536
  int l = i >> 14, rem = i & 16383;
  int a = rem >> 7, b = rem & 127;        // W: a=k,b=c ; Ws: a=c',b=n
  Wtc[(l << 14) + b*128 + a] = f2bf(W[i]);
  Wstc[b*512 + l*128 + a]    = f2bf(Wsm[i]);
  if (i < 27512) zr[i] = make_float4(0.f,0.f,0.f,0.f);
  if (i < 804)   out[i] = 0.f;
}

__global__ void k_count(const int* ei, int* counts){
  int i = blockIdx.x*256 + threadIdx.x;
  if (i >= NG*NE) return;
  int g = i / NE, e = i - g*NE;
  atomicAdd(&counts[g*NN + ei[g*2*NE + NE + e]], 1);
}
__global__ void k_scan(const int* counts, int* offs, int* cursor){
  __shared__ int sm[256];
  int g = blockIdx.x, t = threadIdx.x;
  const int* c = counts + g*NN;
  int i0 = t*24, i1 = i0 + 24; if (i1 > NN) i1 = NN; if (i0 > NN) i0 = NN;
  int s = 0;
  for (int i = i0; i < i1; i++) s += c[i];
  sm[t] = s;
  __syncthreads();
  for (int off = 1; off < 256; off <<= 1){
    int v = (t >= off) ? sm[t - off] : 0;
    __syncthreads();
    sm[t] += v;
    __syncthreads();
  }
  int run = sm[t] - s;
  for (int i = i0; i < i1; i++){
    offs[g*NN + i] = run; cursor[g*NN + i] = run; run += c[i];
  }
}
__global__ void k_place(const int* ei, int* cursor, int2* elist2){
  int i = blockIdx.x*256 + threadIdx.x;
  if (i >= NG*NE) return;
  int g = i / NE, e = i - g*NE;
  int col = ei[g*2*NE + NE + e];
  int row = ei[g*2*NE + e];
  int pos = atomicAdd(&cursor[g*NN + col], 1);
  elist2[g*NE + pos] = make_int2(e, row);
}
__global__ void k_deg(const float* __restrict__ ea, const int* __restrict__ offs,
                      const int* __restrict__ counts, const int2* __restrict__ elist2,
                      float4* __restrict__ dis4){
  int i = blockIdx.x*256 + threadIdx.x;
  if (i >= NG*NN) return;
  int g = i / NN;
  int beg = offs[i], cnt = counts[i];
  const int2* el = elist2 + (size_t)g*NE;
  const float* eag = ea + (size_t)g*NE*6;
  float4 s = make_float4(1.f,1.f,1.f,1.f);
  for (int j = 0; j < cnt; j++){
    int e = el[beg + j].x;
    float2 wa = *(const float2*)(eag + (size_t)e*6 + 2);
    float2 wb = *(const float2*)(eag + (size_t)e*6 + 4);
    s.x += wa.x; s.y += wa.y; s.z += wb.x; s.w += wb.y;
  }
  dis4[i] = make_float4(rsqrtf(fmaxf(s.x,1e-30f)), rsqrtf(fmaxf(s.y,1e-30f)),
                        rsqrtf(fmaxf(s.z,1e-30f)), rsqrtf(fmaxf(s.w,1e-30f)));
}

__global__ void k_cvtx(const float4* x, uint2* xbf, int n4){
  int i = blockIdx.x*256 + threadIdx.x;
  if (i >= n4) return;
  float4 v = x[i];
  xbf[i] = make_uint2((uint)f2bf(v.x) | ((uint)f2bf(v.y) << 16),
                      (uint)f2bf(v.z) | ((uint)f2bf(v.w) << 16));
}

// ---------------- aggregate-first: agg[lg*4+l][n][128] = dn_l*(sum coef*x[r] + dn_l*x[n]) ----------------
__global__ __launch_bounds__(256) void k_gather1(const float* __restrict__ ea,
    const float4* __restrict__ dis4, const int* __restrict__ offs,
    const int* __restrict__ counts, const int2* __restrict__ elist2,
    const ushort* __restrict__ xbf, ushort* __restrict__ agg, int c){
  __shared__ int    sr[4][64];
  __shared__ float4 sc[4][64];
  int lane = threadIdx.x, wy = threadIdx.y;
  int nidx = blockIdx.x*4 + wy;            // 0..11999
  int lg = nidx / NN, n = nidx - lg*NN;
  int g = c*2 + lg;
  float4 dn4 = dis4[g*NN + n];
  const uint* xrow = (const uint*)xbf + (size_t)lg*NN*64;
  uint xv = xrow[(size_t)n*64 + lane];
  f32x2 xs = {bf2f(xv & 0xffffu), bf2f(xv >> 16)};
  f32x2 a0 = xs*dn4.x, a1 = xs*dn4.y, a2 = xs*dn4.z, a3 = xs*dn4.w;
  int beg = offs[g*NN + n], cnt = counts[g*NN + n];
  const int2*  el  = elist2 + (size_t)g*NE;
  const float* eag = ea + (size_t)g*NE*6;
  for (int j0 = 0; j0 < cnt; j0 += 64){
    int take = cnt - j0; if (take > 64) take = 64;
    if (lane < take){
      int2 er = el[beg + j0 + lane];
      float2 wa = *(const float2*)(eag + (size_t)er.x*6 + 2);
      float2 wb = *(const float2*)(eag + (size_t)er.x*6 + 4);
      float4 dr = dis4[g*NN + er.y];
      sr[wy][lane] = er.y;
      sc[wy][lane] = make_float4(wa.x*dr.x, wa.y*dr.y, wb.x*dr.z, wb.y*dr.w);
    }
    int j = 0;
    for (; j + 4 <= take; j += 4){
      int r0 = sr[wy][j], r1 = sr[wy][j+1], r2 = sr[wy][j+2], r3 = sr[wy][j+3];
      float4 c0 = sc[wy][j], c1 = sc[wy][j+1], c2 = sc[wy][j+2], c3 = sc[wy][j+3];
      uint x0 = xrow[(size_t)r0*64 + lane];
      uint x1 = xrow[(size_t)r1*64 + lane];
      uint x2 = xrow[(size_t)r2*64 + lane];
      uint x3 = xrow[(size_t)r3*64 + lane];
      f32x2 v;
      v = (f32x2){bf2f(x0 & 0xffffu), bf2f(x0 >> 16)};
      a0 = v*c0.x + a0; a1 = v*c0.y + a1; a2 = v*c0.z + a2; a3 = v*c0.w + a3;
      v = (f32x2){bf2f(x1 & 0xffffu), bf2f(x1 >> 16)};
      a0 = v*c1.x + a0; a1 = v*c1.y + a1; a2 = v*c1.z + a2; a3 = v*c1.w + a3;
      v = (f32x2){bf2f(x2 & 0xffffu), bf2f(x2 >> 16)};
      a0 = v*c2.x + a0; a1 = v*c2.y + a1; a2 = v*c2.z + a2; a3 = v*c2.w + a3;
      v = (f32x2){bf2f(x3 & 0xffffu), bf2f(x3 >> 16)};
      a0 = v*c3.x + a0; a1 = v*c3.y + a1; a2 = v*c3.z + a2; a3 = v*c3.w + a3;
    }
    for (; j < take; j++){
      int r0 = sr[wy][j];
      float4 c0 = sc[wy][j];
      uint x0 = xrow[(size_t)r0*64 + lane];
      f32x2 v = (f32x2){bf2f(x0 & 0xffffu), bf2f(x0 >> 16)};
      a0 = v*c0.x + a0; a1 = v*c0.y + a1; a2 = v*c0.z + a2; a3 = v*c0.w + a3;
    }
  }
  a0 = a0*dn4.x; a1 = a1*dn4.y; a2 = a2*dn4.z; a3 = a3*dn4.w;
  uint* ag = (uint*)agg;
  ag[((size_t)((lg*4+0)*NN + n))*64 + lane] = (uint)f2bf(a0.x) | ((uint)f2bf(a0.y) << 16);
  ag[((size_t)((lg*4+1)*NN + n))*64 + lane] = (uint)f2bf(a1.x) | ((uint)f2bf(a1.y) << 16);
  ag[((size_t)((lg*4+2)*NN + n))*64 + lane] = (uint)f2bf(a2.x) | ((uint)f2bf(a2.y) << 16);
  ag[((size_t)((lg*4+3)*NN + n))*64 + lane] = (uint)f2bf(a3.x) | ((uint)f2bf(a3.y) << 16);
}

// ---------------- GEMM1: H[lg*NN+row][l*128+col] = relu(agg_l @ W_l + b_l)  (bf16) ----------------
// (R11's fused k_gemmf regressed +70us: only 94 blocks on 256 CUs. Separate
// kernels keep gemm1b at 376 blocks; the H round-trip is the cheaper evil.)
__global__ __launch_bounds__(256) void k_gemm1b(const ushort* __restrict__ agg,
    const ushort* __restrict__ Wtc, const float* __restrict__ gb,
    ushort* __restrict__ H){
  __shared__ ushort As[16384];
  __shared__ ushort Bsh[16384];
  int by = blockIdx.y;            // lg*4 + l
  int lg = by >> 2, l = by & 3;
  int tid = threadIdx.x, w = tid >> 6, lane = tid & 63;
  stage128s(agg + (size_t)by*NN*128 + (size_t)blockIdx.x*16384, 128, As, w, lane);
  stage128s(Wtc + (l << 14), 128, Bsh, w, lane);
  __syncthreads();
  f32x4 acc[4][4];
  zacc(acc);
  mfma128(As, Bsh, w, lane, acc);
  int q = lane >> 4, cl = lane & 15, wm = w >> 1, wn = w & 1;
  int rowb = blockIdx.x*128 + wm*64 + q*4;
  int colb = wn*64 + cl;
  #pragma unroll
  for (int m = 0; m < 4; m++)
    #pragma unroll
    for (int n = 0; n < 4; n++)
      #pragma unroll
      for (int r = 0; r < 4; r++){
        int row = rowb + m*16 + r, col = colb + n*16;
        if (row < NN){
          float v = fmaxf(acc[m][n][r] + gb[l*128 + col], 0.f);
          H[((size_t)(lg*NN + row))*512 + l*128 + col] = f2bf(v);
        }
      }
}

// ---------------- GEMM2: feats[coff+row][128] = H[12000][512] @ Wstc^T (f32) ----------------
__global__ __launch_bounds__(256) void k_gemm2(const ushort* __restrict__ A,
    const ushort* __restrict__ B, float* __restrict__ feats, int coff){
  __shared__ ushort As[16384];
  __shared__ ushort Bsh[16384];
  int tid = threadIdx.x, w = tid >> 6, lane = tid & 63;
  f32x4 acc[4][4];
  zacc(acc);
  #pragma unroll
  for (int kc = 0; kc < 4; kc++){
    if (kc) __syncthreads();
    stage128s(A + (size_t)blockIdx.x*128*512 + kc*128, 512, As, w, lane);
    stage128s(B + kc*128, 512, Bsh, w, lane);
    __syncthreads();
    mfma128(As, Bsh, w, lane, acc);
  }
  int q = lane >> 4, cl = lane & 15, wm = w >> 1, wn = w & 1;
  int rowb = blockIdx.x*128 + wm*64 + q*4;
  int colb = wn*64 + cl;
  #pragma unroll
  for (int m = 0; m < 4; m++)
    #pragma unroll
    for (int n = 0; n < 4; n++)
      #pragma unroll
      for (int r = 0; r < 4; r++){
        int row = rowb + m*16 + r;
        if (row < 2*NN)
          feats[(size_t)(coff + row)*128 + colb + n*16] = acc[m][n][r];
      }
}

__global__ void k_mean(const float* feats, float* out){
  int g = blockIdx.x / 48, ch = blockIdx.x - g*48;
  int c = threadIdx.x;
  float s = 0.f;
  int n0 = ch*125;
  for (int n = n0; n < n0 + 125; n++) s += feats[((size_t)(g*NN + n))*128 + c];
  atomicAdd(&out[g*128 + c], s * (1.0f/6000.0f));
}

// normalize rows -> fp8 e4m3, zero-pad to 6144 rows per graph
__global__ void k_xn(const float* feats, uchar* xn8){
  int lane = threadIdx.x;
  int rall = blockIdx.x*4 + threadIdx.y;   // 0..36863
  int g = rall / NP2, rl = rall - g*NP2;
  ushort* dst = (ushort*)(xn8 + ((size_t)(g*NP2 + rl))*128);
  if (rl < NN){
    const float2* src = (const float2*)&feats[((size_t)(g*NN + rl))*128];
    float2 v = src[lane];
    float ss = v.x*v.x + v.y*v.y;
    #pragma unroll
    for (int s = 32; s > 0; s >>= 1) ss += __shfl_xor(ss, s);
    float inv = 1.0f / fmaxf(sqrtf(ss), 1e-12f);
    int pk = __builtin_amdgcn_cvt_pk_fp8_f32(v.x*inv, v.y*inv, 0, false);
    dst[lane] = (ushort)(pk & 0xffff);
  } else {
    dst[lane] = 0;
  }
}

// ---------------- pairwise v11: MX-FP8 K=128, scalar poly, (256,3) ----------------
// Plateau-proven body (147-150us): scalar psumT, single bfr[4]+acc[4][4] MFMA
// region, no spill (WRITE ~333KB).
__global__ __launch_bounds__(256, 3) void k_pair(const uchar* __restrict__ xn8,
                                                 float* Spart){
  __shared__ uchar Bs[2][8192];
  int bx = blockIdx.x;              // 2664 = 15*144 + 6*84
  int p, rt, c0, niter; bool diag;
  if (bx < 2160){
    int pp = bx / 144, rem = bx - pp*144;
    rt = rem / 6; int ch = rem - rt*6;
    p = c_nd[pp]; diag = false; c0 = ch*16; niter = 16;
  } else {
    int idd = bx - 2160;
    int pd = idd / 84, rem = idd - pd*84;
    int r_ = 0;
    while (c_dcum[r_ + 1] <= rem) r_++;
    rt = r_;
    int ch = rem - c_dcum[rt];
    p = c_dg[pd]; diag = true;
    c0 = 4*rt + ch*16;
    int left = 96 - c0;
    niter = left < 16 ? left : 16;
  }
  int i1 = c_i1[p], i2 = c_i2[p];
  int tid = threadIdx.x, w = tid >> 6, lane = tid & 63;
  int q = lane >> 4, cl = lane & 15;
  // A: 64 rows/wave = 4 m-tiles of 16; lane holds row (cl), k-bytes q*32..+32
  const uchar* Arow = xn8 + ((size_t)i1*NP2 + rt*256 + w*64 + cl)*128 + q*32;
  int8v afr[4];
  #pragma unroll
  for (int m = 0; m < 4; m++){
    uint4 lo = *(const uint4*)(Arow + m*2048);
    uint4 hi = *(const uint4*)(Arow + m*2048 + 16);
    afr[m] = (int8v){(int)lo.x,(int)lo.y,(int)lo.z,(int)lo.w,
                     (int)hi.x,(int)hi.y,(int)hi.z,(int)hi.w};
  }
  // LDS read byte-bases (swizzled), loop-invariant:
  int b0 = cl*128 + (((q*2  ) ^ (cl & 7)) << 4);
  int b1 = cl*128 + (((q*2+1) ^ (cl & 7)) << 4);
  const uchar* Bbase = xn8 + (size_t)i2*NP2*128;
  stage8(Bbase + (size_t)c0*8192, Bs[0], w, lane);
  f32x2 totw = {0.f, 0.f};
  const f32x4 z4 = {0.f,0.f,0.f,0.f};
  for (int it = 0; it < niter; it++){
    int cur = it & 1;
    __syncthreads();                               // drains staging of Bs[cur]
    if (it + 1 < niter)
      stage8(Bbase + (size_t)(c0+it+1)*8192, Bs[1-cur], w, lane);
    __builtin_amdgcn_s_setprio(1);
    int8v bfr[4];
    #pragma unroll
    for (int n = 0; n < 4; n++){
      uint4 lo = *(const uint4*)&Bs[cur][b0 + n*2048];
      uint4 hi = *(const uint4*)&Bs[cur][b1 + n*2048];
      bfr[n] = (int8v){(int)lo.x,(int)lo.y,(int)lo.z,(int)lo.w,
                       (int)hi.x,(int)hi.y,(int)hi.z,(int)hi.w};
    }
    f32x4 acc[4][4];
    #pragma unroll
    for (int m = 0; m < 4; m++)
      #pragma unroll
      for (int n = 0; n < 4; n++)
        acc[m][n] = __builtin_amdgcn_mfma_scale_f32_16x16x128_f8f6f4(
            afr[m], bfr[n], z4, 0, 0, 0, 0x7F, 0, 0x7F);
    __builtin_amdgcn_s_setprio(0);
    f32x2 t2 = psumT(acc);
    float wgt = (diag && (c0 + it) >= 4*rt + 4) ? 2.f : 1.f;
    totw = t2*wgt + totw;
  }
  float tot = totw.x + totw.y;
  #pragma unroll
  for (int s = 32; s > 0; s >>= 1) tot += __shfl_xor(tot, s);
  if (lane == 0) atomicAdd(&Spart[p*64 + (bx & 63)], tot);
}

__global__ void k_final(const float* Spart, float* out){
  int t = threadIdx.x;
  if (t < 21){
    float s = 0.f;
    for (int j = 0; j < 64; j++) s += Spart[t*64 + j];
    float v = s * (1.0f/360000000.0f);
    int i1 = c_i1[t], i2 = c_i2[t];
    out[768 + i1*6 + i2] = v;
    out[768 + i2*6 + i1] = v;
  }
}

extern "C" void kernel_launch(void* const* d_in, const int* in_sizes, int n_in,
                              void* d_out, int out_size, void* d_ws, size_t ws_size,
                              hipStream_t stream){
  (void)in_sizes; (void)n_in; (void)out_size; (void)ws_size;
  const float* x   = (const float*)d_in[0];
  const int*   ei  = (const int*)d_in[1];
  const float* ea  = (const float*)d_in[2];
  const float* gW  = (const float*)d_in[3];
  const float* gb  = (const float*)d_in[4];
  const float* Wsm = (const float*)d_in[5];
  float* out = (float*)d_out;
  char* ws = (char*)d_ws;
  // workspace (bytes), peak ~52.0 MiB
  float*  feats  = (float*) (ws + 0);           // 18,432,000
  int*    counts = (int*)   (ws + 18432000);    //    144,000
  int*    offs   = (int*)   (ws + 18576000);    //    144,000
  int*    cursor = (int*)   (ws + 18720000);    //    144,000
  float*  Spart  = (float*) (ws + 18864000);    //      8,192   [zero 18,432,000..18,872,192)
  float4* dis4   = (float4*)(ws + 18872192);    //    576,000
  int2*   elist2 = (int2*)  (ws + 19448192);    //  4,608,000
  ushort* Wtc    = (ushort*)(ws + 24056192);    //    131,072
  ushort* Wstc   = (ushort*)(ws + 24187264);    //    131,072
  ushort* xbf    = (ushort*)(ws + 24318336);    //  3,072,000
  ushort* agg    = (ushort*)(ws + 27394560);    // 12,288,000 (+8 KB pad)
  ushort* H      = (ushort*)(ws + 39690752);    // 12,320,768 (12032 rows) -> end 52,011,520
  uchar*  xn8    = (uchar*) (ws + 24318336);    //  4,718,592 overlay (xbf/agg dead by k_xn)

  k_init <<<dim3(256),  dim3(256), 0, stream>>>(gW, Wsm, Wtc, Wstc,
                                                (float4*)(ws + 18432000), out);
  k_count<<<dim3(2250), dim3(256), 0, stream>>>(ei, counts);
  k_scan <<<dim3(6),    dim3(256), 0, stream>>>(counts, offs, cursor);
  k_place<<<dim3(2250), dim3(256), 0, stream>>>(ei, cursor, elist2);
  k_deg  <<<dim3(141),  dim3(256), 0, stream>>>(ea, offs, counts, elist2, dis4);
  for (int c = 0; c < 3; c++){
    k_cvtx   <<<dim3(1500), dim3(256), 0, stream>>>(
        (const float4*)(x + (size_t)c*2*NN*128), (uint2*)xbf, 384000);
    k_gather1<<<dim3(3000), dim3(64,4), 0, stream>>>(ea, dis4, offs, counts, elist2,
                                                     xbf, agg, c);
    k_gemm1b <<<dim3(47,8), dim3(256), 0, stream>>>(agg, Wtc, gb, H);
    k_gemm2  <<<dim3(94),   dim3(256), 0, stream>>>(H, Wstc, feats, c*2*NN);
  }
  k_mean <<<dim3(288),  dim3(128),  0, stream>>>(feats, out);
  k_xn   <<<dim3(9216), dim3(64,4), 0, stream>>>(feats, xn8);
  k_pair <<<dim3(2664), dim3(256),  0, stream>>>(xn8, Spart);
  k_final<<<dim3(1),    dim3(64),   0, stream>>>(Spart, out);
}

// Round 13
// 454.885 us; speedup vs baseline: 1.1882x; 1.0403x over previous
//
#include <hip/hip_runtime.h>

#define NG 6
#define NN 6000
#define NE 96000
#define NP2 6144   // 24*256, padded rows per graph for k_pair

typedef unsigned int uint;
typedef unsigned short ushort;
typedef unsigned char uchar;
typedef __attribute__((ext_vector_type(8))) short short8;
typedef __attribute__((ext_vector_type(8))) int int8v;
typedef __attribute__((ext_vector_type(4))) float f32x4;
typedef __attribute__((ext_vector_type(2))) float f32x2;

__device__ __forceinline__ ushort f2bf(float f){
  uint u = __float_as_uint(f);
  u = (u + 0x7fffu + ((u >> 16) & 1u)) >> 16;
  return (ushort)u;
}
__device__ __forceinline__ float bf2f(uint u){ return __uint_as_float(u << 16); }

__device__ __forceinline__ void async16(const void* g, void* l){
  __builtin_amdgcn_global_load_lds(
      (const __attribute__((address_space(1))) unsigned int*)g,
      (__attribute__((address_space(3))) unsigned int*)l, 16, 0, 0);
}

__device__ __constant__ int c_i1[21] = {0,0,0,0,0,0,1,1,1,1,1,2,2,2,2,3,3,3,4,4,5};
__device__ __constant__ int c_i2[21] = {0,1,2,3,4,5,1,2,3,4,5,2,3,4,5,3,4,5,4,5,5};
// non-diag pair ids (15) and diag pair ids (6)
__device__ __constant__ int c_nd[15] = {1,2,3,4,5,7,8,9,10,12,13,14,16,17,19};
__device__ __constant__ int c_dg[6]  = {0,6,11,15,18,20};
// cumulative chunk counts per diag row-tile rt=0..23, chunk=16 col-tiles
__device__ __constant__ int c_dcum[25] = {0,6,12,18,24,29,34,39,44,48,52,56,60,
                                          63,66,69,72,74,76,78,80,81,82,83,84};

// ---------------- MFMA tile helpers (XOR-swizzled LDS, bf16 GEMMs) ----------------
// LDS row r (256B): chunk c at slot c^(r&15).
__device__ __forceinline__ void stage128s(const ushort* __restrict__ gsrc, int stride,
                                          ushort* lds, int w, int lane){
  #pragma unroll
  for (int i = 0; i < 8; i++){
    int off = (w*8 + i) * 512;
    int rowi = (w*8 + i)*4 + (lane >> 4);
    int chunk = (lane & 15) ^ (rowi & 15);
    async16(gsrc + (size_t)rowi*stride + chunk*8, (void*)&lds[off]);
  }
}

// stage a 64-row x 128-byte fp8 tile (8KB): row r (128B = 8 slots of 16B),
// source chunk (slot^(r&7)) lands in slot -> read with same XOR is identity.
__device__ __forceinline__ void stage8(const uchar* __restrict__ gsrc,
                                       uchar* lds, int w, int lane){
  #pragma unroll
  for (int j = 0; j < 2; j++){
    int cj = w*2 + j;
    int d = cj*64 + lane;           // 16B-chunk index 0..511
    int row = d >> 3, slot = d & 7;
    async16(gsrc + (size_t)row*128 + ((slot ^ (row & 7)) << 4),
            (void*)(lds + cj*1024));
  }
}

__device__ __forceinline__ void mfma128(const ushort* As, const ushort* Bs,
                                        int w, int lane, f32x4 acc[4][4]){
  int q = lane >> 4, cl = lane & 15;
  int wm = w >> 1, wn = w & 1;
  #pragma unroll
  for (int ks = 0; ks < 4; ks++){
    short8 af[4], bfr[4];
    int ch = ((ks*4 + q) ^ cl) * 8;
    #pragma unroll
    for (int m = 0; m < 4; m++) af[m]  = *(const short8*)&As[(wm*64 + m*16 + cl)*128 + ch];
    #pragma unroll
    for (int n = 0; n < 4; n++) bfr[n] = *(const short8*)&Bs[(wn*64 + n*16 + cl)*128 + ch];
    #pragma unroll
    for (int m = 0; m < 4; m++)
      #pragma unroll
      for (int n = 0; n < 4; n++)
        acc[m][n] = __builtin_amdgcn_mfma_f32_16x16x32_bf16(af[m], bfr[n], acc[m][n], 0, 0, 0);
  }
}
__device__ __forceinline__ void zacc(f32x4 acc[4][4]){
  #pragma unroll
  for (int m = 0; m < 4; m++)
    #pragma unroll
    for (int n = 0; n < 4; n++) acc[m][n] = (f32x4){0.f,0.f,0.f,0.f};
}

// odd poly: P(d) ~ 10.5*tanh(d) on [-1,1].
// deg-7 via Chebyshev economization of the proven deg-9 (T9 term dropped:
// d^9 ~ (576d^7-432d^5+120d^3-9d)/256; max error |TC9|/256 = 3.3e-4 in P units
// -> <=3.3e-5 in any sim entry, 2 orders below the bf16-path absmax 0.0039).
// Saves 2 of 12 scalar VALU instrs per f32x2 group (~16% of the poly pipe).
#define TD1 10.49617813f
#define TD3 (-3.44980188f)
#define TD5 1.20585508f
#define TD7 (-0.25584007f)
__device__ __forceinline__ f32x2 psumT(const f32x4 acc[4][4]){
  f32x2 t2 = {0.f, 0.f};
  #pragma unroll
  for (int m = 0; m < 4; m++)
    #pragma unroll
    for (int n = 0; n < 4; n++)
      #pragma unroll
      for (int rp = 0; rp < 2; rp++){
        f32x2 d = { acc[m][n][rp*2], acc[m][n][rp*2+1] };
        f32x2 t = d*d;
        f32x2 qq = t*TD7 + TD5;
        qq = qq*t + TD3;
        qq = qq*t + TD1;
        t2 = d*qq + t2;
      }
  return t2;
}

// ---------------- init: zero scratch/out + convert weights (3 launches -> 1) ----------------
// Wtc[l][c][k] = W[l][k][c];  Wstc[n][l*128+c'] = Ws[l][c'][n]
__global__ void k_init(const float* W, const float* Wsm, ushort* Wtc, ushort* Wstc,
                       float4* zr, float* out){
  int i = blockIdx.x*256 + threadIdx.x;   // 65536
  int l = i >> 14, rem = i & 16383;
  int a = rem >> 7, b = rem & 127;        // W: a=k,b=c ; Ws: a=c',b=n
  Wtc[(l << 14) + b*128 + a] = f2bf(W[i]);
  Wstc[b*512 + l*128 + a]    = f2bf(Wsm[i]);
  if (i < 27512) zr[i] = make_float4(0.f,0.f,0.f,0.f);
  if (i < 804)   out[i] = 0.f;
}

__global__ void k_count(const int* ei, int* counts){
  int i = blockIdx.x*256 + threadIdx.x;
  if (i >= NG*NE) return;
  int g = i / NE, e = i - g*NE;
  atomicAdd(&counts[g*NN + ei[g*2*NE + NE + e]], 1);
}
__global__ void k_scan(const int* counts, int* offs, int* cursor){
  __shared__ int sm[256];
  int g = blockIdx.x, t = threadIdx.x;
  const int* c = counts + g*NN;
  int i0 = t*24, i1 = i0 + 24; if (i1 > NN) i1 = NN; if (i0 > NN) i0 = NN;
  int s = 0;
  for (int i = i0; i < i1; i++) s += c[i];
  sm[t] = s;
  __syncthreads();
  for (int off = 1; off < 256; off <<= 1){
    int v = (t >= off) ? sm[t - off] : 0;
    __syncthreads();
    sm[t] += v;
    __syncthreads();
  }
  int run = sm[t] - s;
  for (int i = i0; i < i1; i++){
    offs[g*NN + i] = run; cursor[g*NN + i] = run; run += c[i];
  }
}
__global__ void k_place(const int* ei, int* cursor, int2* elist2){
  int i = blockIdx.x*256 + threadIdx.x;
  if (i >= NG*NE) return;
  int g = i / NE, e = i - g*NE;
  int col = ei[g*2*NE + NE + e];
  int row = ei[g*2*NE + e];
  int pos = atomicAdd(&cursor[g*NN + col], 1);
  elist2[g*NE + pos] = make_int2(e, row);
}
__global__ void k_deg(const float* __restrict__ ea, const int* __restrict__ offs,
                      const int* __restrict__ counts, const int2* __restrict__ elist2,
                      float4* __restrict__ dis4){
  int i = blockIdx.x*256 + threadIdx.x;
  if (i >= NG*NN) return;
  int g = i / NN;
  int beg = offs[i], cnt = counts[i];
  const int2* el = elist2 + (size_t)g*NE;
  const float* eag = ea + (size_t)g*NE*6;
  float4 s = make_float4(1.f,1.f,1.f,1.f);
  for (int j = 0; j < cnt; j++){
    int e = el[beg + j].x;
    float2 wa = *(const float2*)(eag + (size_t)e*6 + 2);
    float2 wb = *(const float2*)(eag + (size_t)e*6 + 4);
    s.x += wa.x; s.y += wa.y; s.z += wb.x; s.w += wb.y;
  }
  dis4[i] = make_float4(rsqrtf(fmaxf(s.x,1e-30f)), rsqrtf(fmaxf(s.y,1e-30f)),
                        rsqrtf(fmaxf(s.z,1e-30f)), rsqrtf(fmaxf(s.w,1e-30f)));
}

__global__ void k_cvtx(const float4* x, uint2* xbf, int n4){
  int i = blockIdx.x*256 + threadIdx.x;
  if (i >= n4) return;
  float4 v = x[i];
  xbf[i] = make_uint2((uint)f2bf(v.x) | ((uint)f2bf(v.y) << 16),
                      (uint)f2bf(v.z) | ((uint)f2bf(v.w) << 16));
}

// ---------------- aggregate-first: agg[lg*4+l][n][128] = dn_l*(sum coef*x[r] + dn_l*x[n]) ----------------
__global__ __launch_bounds__(256) void k_gather1(const float* __restrict__ ea,
    const float4* __restrict__ dis4, const int* __restrict__ offs,
    const int* __restrict__ counts, const int2* __restrict__ elist2,
    const ushort* __restrict__ xbf, ushort* __restrict__ agg, int c){
  __shared__ int    sr[4][64];
  __shared__ float4 sc[4][64];
  int lane = threadIdx.x, wy = threadIdx.y;
  int nidx = blockIdx.x*4 + wy;            // 0..11999
  int lg = nidx / NN, n = nidx - lg*NN;
  int g = c*2 + lg;
  float4 dn4 = dis4[g*NN + n];
  const uint* xrow = (const uint*)xbf + (size_t)lg*NN*64;
  uint xv = xrow[(size_t)n*64 + lane];
  f32x2 xs = {bf2f(xv & 0xffffu), bf2f(xv >> 16)};
  f32x2 a0 = xs*dn4.x, a1 = xs*dn4.y, a2 = xs*dn4.z, a3 = xs*dn4.w;
  int beg = offs[g*NN + n], cnt = counts[g*NN + n];
  const int2*  el  = elist2 + (size_t)g*NE;
  const float* eag = ea + (size_t)g*NE*6;
  for (int j0 = 0; j0 < cnt; j0 += 64){
    int take = cnt - j0; if (take > 64) take = 64;
    if (lane < take){
      int2 er = el[beg + j0 + lane];
      float2 wa = *(const float2*)(eag + (size_t)er.x*6 + 2);
      float2 wb = *(const float2*)(eag + (size_t)er.x*6 + 4);
      float4 dr = dis4[g*NN + er.y];
      sr[wy][lane] = er.y;
      sc[wy][lane] = make_float4(wa.x*dr.x, wa.y*dr.y, wb.x*dr.z, wb.y*dr.w);
    }
    int j = 0;
    for (; j + 4 <= take; j += 4){
      int r0 = sr[wy][j], r1 = sr[wy][j+1], r2 = sr[wy][j+2], r3 = sr[wy][j+3];
      float4 c0 = sc[wy][j], c1 = sc[wy][j+1], c2 = sc[wy][j+2], c3 = sc[wy][j+3];
      uint x0 = xrow[(size_t)r0*64 + lane];
      uint x1 = xrow[(size_t)r1*64 + lane];
      uint x2 = xrow[(size_t)r2*64 + lane];
      uint x3 = xrow[(size_t)r3*64 + lane];
      f32x2 v;
      v = (f32x2){bf2f(x0 & 0xffffu), bf2f(x0 >> 16)};
      a0 = v*c0.x + a0; a1 = v*c0.y + a1; a2 = v*c0.z + a2; a3 = v*c0.w + a3;
      v = (f32x2){bf2f(x1 & 0xffffu), bf2f(x1 >> 16)};
      a0 = v*c1.x + a0; a1 = v*c1.y + a1; a2 = v*c1.z + a2; a3 = v*c1.w + a3;
      v = (f32x2){bf2f(x2 & 0xffffu), bf2f(x2 >> 16)};
      a0 = v*c2.x + a0; a1 = v*c2.y + a1; a2 = v*c2.z + a2; a3 = v*c2.w + a3;
      v = (f32x2){bf2f(x3 & 0xffffu), bf2f(x3 >> 16)};
      a0 = v*c3.x + a0; a1 = v*c3.y + a1; a2 = v*c3.z + a2; a3 = v*c3.w + a3;
    }
    for (; j < take; j++){
      int r0 = sr[wy][j];
      float4 c0 = sc[wy][j];
      uint x0 = xrow[(size_t)r0*64 + lane];
      f32x2 v = (f32x2){bf2f(x0 & 0xffffu), bf2f(x0 >> 16)};
      a0 = v*c0.x + a0; a1 = v*c0.y + a1; a2 = v*c0.z + a2; a3 = v*c0.w + a3;
    }
  }
  a0 = a0*dn4.x; a1 = a1*dn4.y; a2 = a2*dn4.z; a3 = a3*dn4.w;
  uint* ag = (uint*)agg;
  ag[((size_t)((lg*4+0)*NN + n))*64 + lane] = (uint)f2bf(a0.x) | ((uint)f2bf(a0.y) << 16);
  ag[((size_t)((lg*4+1)*NN + n))*64 + lane] = (uint)f2bf(a1.x) | ((uint)f2bf(a1.y) << 16);
  ag[((size_t)((lg*4+2)*NN + n))*64 + lane] = (uint)f2bf(a2.x) | ((uint)f2bf(a2.y) << 16);
  ag[((size_t)((lg*4+3)*NN + n))*64 + lane] = (uint)f2bf(a3.x) | ((uint)f2bf(a3.y) << 16);
}

// ---------------- GEMM1: H[lg*NN+row][l*128+col] = relu(agg_l @ W_l + b_l)  (bf16) ----------------
// (R11's fused k_gemmf regressed +70us: only 94 blocks on 256 CUs. Separate
// kernels keep gemm1b at 376 blocks; the H round-trip is the cheaper evil.)
__global__ __launch_bounds__(256) void k_gemm1b(const ushort* __restrict__ agg,
    const ushort* __restrict__ Wtc, const float* __restrict__ gb,
    ushort* __restrict__ H){
  __shared__ ushort As[16384];
  __shared__ ushort Bsh[16384];
  int by = blockIdx.y;            // lg*4 + l
  int lg = by >> 2, l = by & 3;
  int tid = threadIdx.x, w = tid >> 6, lane = tid & 63;
  stage128s(agg + (size_t)by*NN*128 + (size_t)blockIdx.x*16384, 128, As, w, lane);
  stage128s(Wtc + (l << 14), 128, Bsh, w, lane);
  __syncthreads();
  f32x4 acc[4][4];
  zacc(acc);
  mfma128(As, Bsh, w, lane, acc);
  int q = lane >> 4, cl = lane & 15, wm = w >> 1, wn = w & 1;
  int rowb = blockIdx.x*128 + wm*64 + q*4;
  int colb = wn*64 + cl;
  #pragma unroll
  for (int m = 0; m < 4; m++)
    #pragma unroll
    for (int n = 0; n < 4; n++)
      #pragma unroll
      for (int r = 0; r < 4; r++){
        int row = rowb + m*16 + r, col = colb + n*16;
        if (row < NN){
          float v = fmaxf(acc[m][n][r] + gb[l*128 + col], 0.f);
          H[((size_t)(lg*NN + row))*512 + l*128 + col] = f2bf(v);
        }
      }
}

// ---------------- GEMM2: feats[coff+row][128] = H[12000][512] @ Wstc^T (f32) ----------------
__global__ __launch_bounds__(256) void k_gemm2(const ushort* __restrict__ A,
    const ushort* __restrict__ B, float* __restrict__ feats, int coff){
  __shared__ ushort As[16384];
  __shared__ ushort Bsh[16384];
  int tid = threadIdx.x, w = tid >> 6, lane = tid & 63;
  f32x4 acc[4][4];
  zacc(acc);
  #pragma unroll
  for (int kc = 0; kc < 4; kc++){
    if (kc) __syncthreads();
    stage128s(A + (size_t)blockIdx.x*128*512 + kc*128, 512, As, w, lane);
    stage128s(B + kc*128, 512, Bsh, w, lane);
    __syncthreads();
    mfma128(As, Bsh, w, lane, acc);
  }
  int q = lane >> 4, cl = lane & 15, wm = w >> 1, wn = w & 1;
  int rowb = blockIdx.x*128 + wm*64 + q*4;
  int colb = wn*64 + cl;
  #pragma unroll
  for (int m = 0; m < 4; m++)
    #pragma unroll
    for (int n = 0; n < 4; n++)
      #pragma unroll
      for (int r = 0; r < 4; r++){
        int row = rowb + m*16 + r;
        if (row < 2*NN)
          feats[(size_t)(coff + row)*128 + colb + n*16] = acc[m][n][r];
      }
}

__global__ void k_mean(const float* feats, float* out){
  int g = blockIdx.x / 48, ch = blockIdx.x - g*48;
  int c = threadIdx.x;
  float s = 0.f;
  int n0 = ch*125;
  for (int n = n0; n < n0 + 125; n++) s += feats[((size_t)(g*NN + n))*128 + c];
  atomicAdd(&out[g*128 + c], s * (1.0f/6000.0f));
}

// normalize rows -> fp8 e4m3, zero-pad to 6144 rows per graph
__global__ void k_xn(const float* feats, uchar* xn8){
  int lane = threadIdx.x;
  int rall = blockIdx.x*4 + threadIdx.y;   // 0..36863
  int g = rall / NP2, rl = rall - g*NP2;
  ushort* dst = (ushort*)(xn8 + ((size_t)(g*NP2 + rl))*128);
  if (rl < NN){
    const float2* src = (const float2*)&feats[((size_t)(g*NN + rl))*128];
    float2 v = src[lane];
    float ss = v.x*v.x + v.y*v.y;
    #pragma unroll
    for (int s = 32; s > 0; s >>= 1) ss += __shfl_xor(ss, s);
    float inv = 1.0f / fmaxf(sqrtf(ss), 1e-12f);
    int pk = __builtin_amdgcn_cvt_pk_fp8_f32(v.x*inv, v.y*inv, 0, false);
    dst[lane] = (ushort)(pk & 0xffff);
  } else {
    dst[lane] = 0;
  }
}

// ---------------- pairwise v12: MX-FP8 K=128, deg-7 economized poly, (256,3) ----------------
// Plateau-proven body (145-150us): single bfr[4]+acc[4][4] MFMA region, no
// spill (WRITE ~333KB). Only delta vs v11: deg-9 -> deg-7 poly (see psumT).
__global__ __launch_bounds__(256, 3) void k_pair(const uchar* __restrict__ xn8,
                                                 float* Spart){
  __shared__ uchar Bs[2][8192];
  int bx = blockIdx.x;              // 2664 = 15*144 + 6*84
  int p, rt, c0, niter; bool diag;
  if (bx < 2160){
    int pp = bx / 144, rem = bx - pp*144;
    rt = rem / 6; int ch = rem - rt*6;
    p = c_nd[pp]; diag = false; c0 = ch*16; niter = 16;
  } else {
    int idd = bx - 2160;
    int pd = idd / 84, rem = idd - pd*84;
    int r_ = 0;
    while (c_dcum[r_ + 1] <= rem) r_++;
    rt = r_;
    int ch = rem - c_dcum[rt];
    p = c_dg[pd]; diag = true;
    c0 = 4*rt + ch*16;
    int left = 96 - c0;
    niter = left < 16 ? left : 16;
  }
  int i1 = c_i1[p], i2 = c_i2[p];
  int tid = threadIdx.x, w = tid >> 6, lane = tid & 63;
  int q = lane >> 4, cl = lane & 15;
  // A: 64 rows/wave = 4 m-tiles of 16; lane holds row (cl), k-bytes q*32..+32
  const uchar* Arow = xn8 + ((size_t)i1*NP2 + rt*256 + w*64 + cl)*128 + q*32;
  int8v afr[4];
  #pragma unroll
  for (int m = 0; m < 4; m++){
    uint4 lo = *(const uint4*)(Arow + m*2048);
    uint4 hi = *(const uint4*)(Arow + m*2048 + 16);
    afr[m] = (int8v){(int)lo.x,(int)lo.y,(int)lo.z,(int)lo.w,
                     (int)hi.x,(int)hi.y,(int)hi.z,(int)hi.w};
  }
  // LDS read byte-bases (swizzled), loop-invariant:
  int b0 = cl*128 + (((q*2  ) ^ (cl & 7)) << 4);
  int b1 = cl*128 + (((q*2+1) ^ (cl & 7)) << 4);
  const uchar* Bbase = xn8 + (size_t)i2*NP2*128;
  stage8(Bbase + (size_t)c0*8192, Bs[0], w, lane);
  f32x2 totw = {0.f, 0.f};
  const f32x4 z4 = {0.f,0.f,0.f,0.f};
  for (int it = 0; it < niter; it++){
    int cur = it & 1;
    __syncthreads();                               // drains staging of Bs[cur]
    if (it + 1 < niter)
      stage8(Bbase + (size_t)(c0+it+1)*8192, Bs[1-cur], w, lane);
    __builtin_amdgcn_s_setprio(1);
    int8v bfr[4];
    #pragma unroll
    for (int n = 0; n < 4; n++){
      uint4 lo = *(const uint4*)&Bs[cur][b0 + n*2048];
      uint4 hi = *(const uint4*)&Bs[cur][b1 + n*2048];
      bfr[n] = (int8v){(int)lo.x,(int)lo.y,(int)lo.z,(int)lo.w,
                       (int)hi.x,(int)hi.y,(int)hi.z,(int)hi.w};
    }
    f32x4 acc[4][4];
    #pragma unroll
    for (int m = 0; m < 4; m++)
      #pragma unroll
      for (int n = 0; n < 4; n++)
        acc[m][n] = __builtin_amdgcn_mfma_scale_f32_16x16x128_f8f6f4(
            afr[m], bfr[n], z4, 0, 0, 0, 0x7F, 0, 0x7F);
    __builtin_amdgcn_s_setprio(0);
    f32x2 t2 = psumT(acc);
    float wgt = (diag && (c0 + it) >= 4*rt + 4) ? 2.f : 1.f;
    totw = t2*wgt + totw;
  }
  float tot = totw.x + totw.y;
  #pragma unroll
  for (int s = 32; s > 0; s >>= 1) tot += __shfl_xor(tot, s);
  if (lane == 0) atomicAdd(&Spart[p*64 + (bx & 63)], tot);
}

__global__ void k_final(const float* Spart, float* out){
  int t = threadIdx.x;
  if (t < 21){
    float s = 0.f;
    for (int j = 0; j < 64; j++) s += Spart[t*64 + j];
    float v = s * (1.0f/360000000.0f);
    int i1 = c_i1[t], i2 = c_i2[t];
    out[768 + i1*6 + i2] = v;
    out[768 + i2*6 + i1] = v;
  }
}

extern "C" void kernel_launch(void* const* d_in, const int* in_sizes, int n_in,
                              void* d_out, int out_size, void* d_ws, size_t ws_size,
                              hipStream_t stream){
  (void)in_sizes; (void)n_in; (void)out_size; (void)ws_size;
  const float* x   = (const float*)d_in[0];
  const int*   ei  = (const int*)d_in[1];
  const float* ea  = (const float*)d_in[2];
  const float* gW  = (const float*)d_in[3];
  const float* gb  = (const float*)d_in[4];
  const float* Wsm = (const float*)d_in[5];
  float* out = (float*)d_out;
  char* ws = (char*)d_ws;
  // workspace (bytes), peak ~52.0 MiB
  float*  feats  = (float*) (ws + 0);           // 18,432,000
  int*    counts = (int*)   (ws + 18432000);    //    144,000
  int*    offs   = (int*)   (ws + 18576000);    //    144,000
  int*    cursor = (int*)   (ws + 18720000);    //    144,000
  float*  Spart  = (float*) (ws + 18864000);    //      8,192   [zero 18,432,000..18,872,192)
  float4* dis4   = (float4*)(ws + 18872192);    //    576,000
  int2*   elist2 = (int2*)  (ws + 19448192);    //  4,608,000
  ushort* Wtc    = (ushort*)(ws + 24056192);    //    131,072
  ushort* Wstc   = (ushort*)(ws + 24187264);    //    131,072
  ushort* xbf    = (ushort*)(ws + 24318336);    //  3,072,000
  ushort* agg    = (ushort*)(ws + 27394560);    // 12,288,000 (+8 KB pad)
  ushort* H      = (ushort*)(ws + 39690752);    // 12,320,768 (12032 rows) -> end 52,011,520
  uchar*  xn8    = (uchar*) (ws + 24318336);    //  4,718,592 overlay (xbf/agg dead by k_xn)

  k_init <<<dim3(256),  dim3(256), 0, stream>>>(gW, Wsm, Wtc, Wstc,
                                                (float4*)(ws + 18432000), out);
  k_count<<<dim3(2250), dim3(256), 0, stream>>>(ei, counts);
  k_scan <<<dim3(6),    dim3(256), 0, stream>>>(counts, offs, cursor);
  k_place<<<dim3(2250), dim3(256), 0, stream>>>(ei, cursor, elist2);
  k_deg  <<<dim3(141),  dim3(256), 0, stream>>>(ea, offs, counts, elist2, dis4);
  for (int c = 0; c < 3; c++){
    k_cvtx   <<<dim3(1500), dim3(256), 0, stream>>>(
        (const float4*)(x + (size_t)c*2*NN*128), (uint2*)xbf, 384000);
    k_gather1<<<dim3(3000), dim3(64,4), 0, stream>>>(ea, dis4, offs, counts, elist2,
                                                     xbf, agg, c);
    k_gemm1b <<<dim3(47,8), dim3(256), 0, stream>>>(agg, Wtc, gb, H);
    k_gemm2  <<<dim3(94),   dim3(256), 0, stream>>>(H, Wstc, feats, c*2*NN);
  }
  k_mean <<<dim3(288),  dim3(128),  0, stream>>>(feats, out);
  k_xn   <<<dim3(9216), dim3(64,4), 0, stream>>>(feats, xn8);
  k_pair <<<dim3(2664), dim3(256),  0, stream>>>(xn8, Spart);
  k_final<<<dim3(1),    dim3(64),   0, stream>>>(Spart, out);
}

// Round 14
// 448.452 us; speedup vs baseline: 1.2053x; 1.0143x over previous
//
#include <hip/hip_runtime.h>

#define NG 6
#define NN 6000
#define NE 96000
#define NP2 6144   // 24*256, padded rows per graph for k_pair

typedef unsigned int uint;
typedef unsigned short ushort;
typedef unsigned char uchar;
typedef __attribute__((ext_vector_type(8))) short short8;
typedef __attribute__((ext_vector_type(8))) int int8v;
typedef __attribute__((ext_vector_type(4))) float f32x4;
typedef __attribute__((ext_vector_type(2))) float f32x2;

__device__ __forceinline__ ushort f2bf(float f){
  uint u = __float_as_uint(f);
  u = (u + 0x7fffu + ((u >> 16) & 1u)) >> 16;
  return (ushort)u;
}
__device__ __forceinline__ float bf2f(uint u){ return __uint_as_float(u << 16); }

__device__ __forceinline__ void async16(const void* g, void* l){
  __builtin_amdgcn_global_load_lds(
      (const __attribute__((address_space(1))) unsigned int*)g,
      (__attribute__((address_space(3))) unsigned int*)l, 16, 0, 0);
}

__device__ __constant__ int c_i1[21] = {0,0,0,0,0,0,1,1,1,1,1,2,2,2,2,3,3,3,4,4,5};
__device__ __constant__ int c_i2[21] = {0,1,2,3,4,5,1,2,3,4,5,2,3,4,5,3,4,5,4,5,5};
// non-diag pair ids (15) and diag pair ids (6)
__device__ __constant__ int c_nd[15] = {1,2,3,4,5,7,8,9,10,12,13,14,16,17,19};
__device__ __constant__ int c_dg[6]  = {0,6,11,15,18,20};
// cumulative chunk counts per diag row-tile rt=0..23, chunk=16 col-tiles
__device__ __constant__ int c_dcum[25] = {0,6,12,18,24,29,34,39,44,48,52,56,60,
                                          63,66,69,72,74,76,78,80,81,82,83,84};

// ---------------- MFMA tile helpers (XOR-swizzled LDS, bf16 GEMMs) ----------------
// LDS row r (256B): chunk c at slot c^(r&15).
__device__ __forceinline__ void stage128s(const ushort* __restrict__ gsrc, int stride,
                                          ushort* lds, int w, int lane){
  #pragma unroll
  for (int i = 0; i < 8; i++){
    int off = (w*8 + i) * 512;
    int rowi = (w*8 + i)*4 + (lane >> 4);
    int chunk = (lane & 15) ^ (rowi & 15);
    async16(gsrc + (size_t)rowi*stride + chunk*8, (void*)&lds[off]);
  }
}

// stage a 64-row x 128-byte fp8 tile (8KB): row r (128B = 8 slots of 16B),
// source chunk (slot^(r&7)) lands in slot -> read with same XOR is identity.
__device__ __forceinline__ void stage8(const uchar* __restrict__ gsrc,
                                       uchar* lds, int w, int lane){
  #pragma unroll
  for (int j = 0; j < 2; j++){
    int cj = w*2 + j;
    int d = cj*64 + lane;           // 16B-chunk index 0..511
    int row = d >> 3, slot = d & 7;
    async16(gsrc + (size_t)row*128 + ((slot ^ (row & 7)) << 4),
            (void*)(lds + cj*1024));
  }
}

__device__ __forceinline__ void mfma128(const ushort* As, const ushort* Bs,
                                        int w, int lane, f32x4 acc[4][4]){
  int q = lane >> 4, cl = lane & 15;
  int wm = w >> 1, wn = w & 1;
  #pragma unroll
  for (int ks = 0; ks < 4; ks++){
    short8 af[4], bfr[4];
    int ch = ((ks*4 + q) ^ cl) * 8;
    #pragma unroll
    for (int m = 0; m < 4; m++) af[m]  = *(const short8*)&As[(wm*64 + m*16 + cl)*128 + ch];
    #pragma unroll
    for (int n = 0; n < 4; n++) bfr[n] = *(const short8*)&Bs[(wn*64 + n*16 + cl)*128 + ch];
    #pragma unroll
    for (int m = 0; m < 4; m++)
      #pragma unroll
      for (int n = 0; n < 4; n++)
        acc[m][n] = __builtin_amdgcn_mfma_f32_16x16x32_bf16(af[m], bfr[n], acc[m][n], 0, 0, 0);
  }
}
__device__ __forceinline__ void zacc(f32x4 acc[4][4]){
  #pragma unroll
  for (int m = 0; m < 4; m++)
    #pragma unroll
    for (int n = 0; n < 4; n++) acc[m][n] = (f32x4){0.f,0.f,0.f,0.f};
}

// odd poly: P(d) ~ 10.5*tanh(d) on [-1,1].
// deg-5 via two-step Chebyshev economization of the proven deg-9:
//   R13 (deg-7, err 3.3e-4 P-units) -> drop T7 of d^7:
//   d^7 ~ (112d^5 - 56d^3 + 7d)/64, added err |TD7|/64 = 4.0e-3 P-units
//   -> <= 4.0e-4 per sim entry after /360e6 norm (37x under threshold; T7
//   oscillation averages it further down). P5(1)=8.000 vs 10.5tanh(1)=7.996.
// 8 scalar VALU instrs per f32x2 group (was 10 deg-7, 12 deg-9).
#define TE1 10.46819562f
#define TE3 (-3.22594182f)
#define TE5 0.75813496f
__device__ __forceinline__ f32x2 psumT(const f32x4 acc[4][4]){
  f32x2 t2 = {0.f, 0.f};
  #pragma unroll
  for (int m = 0; m < 4; m++)
    #pragma unroll
    for (int n = 0; n < 4; n++)
      #pragma unroll
      for (int rp = 0; rp < 2; rp++){
        f32x2 d = { acc[m][n][rp*2], acc[m][n][rp*2+1] };
        f32x2 t = d*d;
        f32x2 qq = t*TE5 + TE3;
        qq = qq*t + TE1;
        t2 = d*qq + t2;
      }
  return t2;
}

// ---------------- init: zero scratch/out + convert weights (3 launches -> 1) ----------------
// Wtc[l][c][k] = W[l][k][c];  Wstc[n][l*128+c'] = Ws[l][c'][n]
__global__ void k_init(const float* W, const float* Wsm, ushort* Wtc, ushort* Wstc,
                       float4* zr, float* out){
  int i = blockIdx.x*256 + threadIdx.x;   // 65536
  int l = i >> 14, rem = i & 16383;
  int a = rem >> 7, b = rem & 127;        // W: a=k,b=c ; Ws: a=c',b=n
  Wtc[(l << 14) + b*128 + a] = f2bf(W[i]);
  Wstc[b*512 + l*128 + a]    = f2bf(Wsm[i]);
  if (i < 27512) zr[i] = make_float4(0.f,0.f,0.f,0.f);
  if (i < 804)   out[i] = 0.f;
}

__global__ void k_count(const int* ei, int* counts){
  int i = blockIdx.x*256 + threadIdx.x;
  if (i >= NG*NE) return;
  int g = i / NE, e = i - g*NE;
  atomicAdd(&counts[g*NN + ei[g*2*NE + NE + e]], 1);
}
__global__ void k_scan(const int* counts, int* offs, int* cursor){
  __shared__ int sm[256];
  int g = blockIdx.x, t = threadIdx.x;
  const int* c = counts + g*NN;
  int i0 = t*24, i1 = i0 + 24; if (i1 > NN) i1 = NN; if (i0 > NN) i0 = NN;
  int s = 0;
  for (int i = i0; i < i1; i++) s += c[i];
  sm[t] = s;
  __syncthreads();
  for (int off = 1; off < 256; off <<= 1){
    int v = (t >= off) ? sm[t - off] : 0;
    __syncthreads();
    sm[t] += v;
    __syncthreads();
  }
  int run = sm[t] - s;
  for (int i = i0; i < i1; i++){
    offs[g*NN + i] = run; cursor[g*NN + i] = run; run += c[i];
  }
}
__global__ void k_place(const int* ei, int* cursor, int2* elist2){
  int i = blockIdx.x*256 + threadIdx.x;
  if (i >= NG*NE) return;
  int g = i / NE, e = i - g*NE;
  int col = ei[g*2*NE + NE + e];
  int row = ei[g*2*NE + e];
  int pos = atomicAdd(&cursor[g*NN + col], 1);
  elist2[g*NE + pos] = make_int2(e, row);
}
__global__ void k_deg(const float* __restrict__ ea, const int* __restrict__ offs,
                      const int* __restrict__ counts, const int2* __restrict__ elist2,
                      float4* __restrict__ dis4){
  int i = blockIdx.x*256 + threadIdx.x;
  if (i >= NG*NN) return;
  int g = i / NN;
  int beg = offs[i], cnt = counts[i];
  const int2* el = elist2 + (size_t)g*NE;
  const float* eag = ea + (size_t)g*NE*6;
  float4 s = make_float4(1.f,1.f,1.f,1.f);
  for (int j = 0; j < cnt; j++){
    int e = el[beg + j].x;
    float2 wa = *(const float2*)(eag + (size_t)e*6 + 2);
    float2 wb = *(const float2*)(eag + (size_t)e*6 + 4);
    s.x += wa.x; s.y += wa.y; s.z += wb.x; s.w += wb.y;
  }
  dis4[i] = make_float4(rsqrtf(fmaxf(s.x,1e-30f)), rsqrtf(fmaxf(s.y,1e-30f)),
                        rsqrtf(fmaxf(s.z,1e-30f)), rsqrtf(fmaxf(s.w,1e-30f)));
}

__global__ void k_cvtx(const float4* x, uint2* xbf, int n4){
  int i = blockIdx.x*256 + threadIdx.x;
  if (i >= n4) return;
  float4 v = x[i];
  xbf[i] = make_uint2((uint)f2bf(v.x) | ((uint)f2bf(v.y) << 16),
                      (uint)f2bf(v.z) | ((uint)f2bf(v.w) << 16));
}

// ---------------- aggregate-first: agg[lg*4+l][n][128] = dn_l*(sum coef*x[r] + dn_l*x[n]) ----------------
__global__ __launch_bounds__(256) void k_gather1(const float* __restrict__ ea,
    const float4* __restrict__ dis4, const int* __restrict__ offs,
    const int* __restrict__ counts, const int2* __restrict__ elist2,
    const ushort* __restrict__ xbf, ushort* __restrict__ agg, int c){
  __shared__ int    sr[4][64];
  __shared__ float4 sc[4][64];
  int lane = threadIdx.x, wy = threadIdx.y;
  int nidx = blockIdx.x*4 + wy;            // 0..11999
  int lg = nidx / NN, n = nidx - lg*NN;
  int g = c*2 + lg;
  float4 dn4 = dis4[g*NN + n];
  const uint* xrow = (const uint*)xbf + (size_t)lg*NN*64;
  uint xv = xrow[(size_t)n*64 + lane];
  f32x2 xs = {bf2f(xv & 0xffffu), bf2f(xv >> 16)};
  f32x2 a0 = xs*dn4.x, a1 = xs*dn4.y, a2 = xs*dn4.z, a3 = xs*dn4.w;
  int beg = offs[g*NN + n], cnt = counts[g*NN + n];
  const int2*  el  = elist2 + (size_t)g*NE;
  const float* eag = ea + (size_t)g*NE*6;
  for (int j0 = 0; j0 < cnt; j0 += 64){
    int take = cnt - j0; if (take > 64) take = 64;
    if (lane < take){
      int2 er = el[beg + j0 + lane];
      float2 wa = *(const float2*)(eag + (size_t)er.x*6 + 2);
      float2 wb = *(const float2*)(eag + (size_t)er.x*6 + 4);
      float4 dr = dis4[g*NN + er.y];
      sr[wy][lane] = er.y;
      sc[wy][lane] = make_float4(wa.x*dr.x, wa.y*dr.y, wb.x*dr.z, wb.y*dr.w);
    }
    int j = 0;
    for (; j + 4 <= take; j += 4){
      int r0 = sr[wy][j], r1 = sr[wy][j+1], r2 = sr[wy][j+2], r3 = sr[wy][j+3];
      float4 c0 = sc[wy][j], c1 = sc[wy][j+1], c2 = sc[wy][j+2], c3 = sc[wy][j+3];
      uint x0 = xrow[(size_t)r0*64 + lane];
      uint x1 = xrow[(size_t)r1*64 + lane];
      uint x2 = xrow[(size_t)r2*64 + lane];
      uint x3 = xrow[(size_t)r3*64 + lane];
      f32x2 v;
      v = (f32x2){bf2f(x0 & 0xffffu), bf2f(x0 >> 16)};
      a0 = v*c0.x + a0; a1 = v*c0.y + a1; a2 = v*c0.z + a2; a3 = v*c0.w + a3;
      v = (f32x2){bf2f(x1 & 0xffffu), bf2f(x1 >> 16)};
      a0 = v*c1.x + a0; a1 = v*c1.y + a1; a2 = v*c1.z + a2; a3 = v*c1.w + a3;
      v = (f32x2){bf2f(x2 & 0xffffu), bf2f(x2 >> 16)};
      a0 = v*c2.x + a0; a1 = v*c2.y + a1; a2 = v*c2.z + a2; a3 = v*c2.w + a3;
      v = (f32x2){bf2f(x3 & 0xffffu), bf2f(x3 >> 16)};
      a0 = v*c3.x + a0; a1 = v*c3.y + a1; a2 = v*c3.z + a2; a3 = v*c3.w + a3;
    }
    for (; j < take; j++){
      int r0 = sr[wy][j];
      float4 c0 = sc[wy][j];
      uint x0 = xrow[(size_t)r0*64 + lane];
      f32x2 v = (f32x2){bf2f(x0 & 0xffffu), bf2f(x0 >> 16)};
      a0 = v*c0.x + a0; a1 = v*c0.y + a1; a2 = v*c0.z + a2; a3 = v*c0.w + a3;
    }
  }
  a0 = a0*dn4.x; a1 = a1*dn4.y; a2 = a2*dn4.z; a3 = a3*dn4.w;
  uint* ag = (uint*)agg;
  ag[((size_t)((lg*4+0)*NN + n))*64 + lane] = (uint)f2bf(a0.x) | ((uint)f2bf(a0.y) << 16);
  ag[((size_t)((lg*4+1)*NN + n))*64 + lane] = (uint)f2bf(a1.x) | ((uint)f2bf(a1.y) << 16);
  ag[((size_t)((lg*4+2)*NN + n))*64 + lane] = (uint)f2bf(a2.x) | ((uint)f2bf(a2.y) << 16);
  ag[((size_t)((lg*4+3)*NN + n))*64 + lane] = (uint)f2bf(a3.x) | ((uint)f2bf(a3.y) << 16);
}

// ---------------- GEMM1: H[lg*NN+row][l*128+col] = relu(agg_l @ W_l + b_l)  (bf16) ----------------
// (R11's fused k_gemmf regressed +70us: only 94 blocks on 256 CUs. Separate
// kernels keep gemm1b at 376 blocks; the H round-trip is the cheaper evil.)
__global__ __launch_bounds__(256) void k_gemm1b(const ushort* __restrict__ agg,
    const ushort* __restrict__ Wtc, const float* __restrict__ gb,
    ushort* __restrict__ H){
  __shared__ ushort As[16384];
  __shared__ ushort Bsh[16384];
  int by = blockIdx.y;            // lg*4 + l
  int lg = by >> 2, l = by & 3;
  int tid = threadIdx.x, w = tid >> 6, lane = tid & 63;
  stage128s(agg + (size_t)by*NN*128 + (size_t)blockIdx.x*16384, 128, As, w, lane);
  stage128s(Wtc + (l << 14), 128, Bsh, w, lane);
  __syncthreads();
  f32x4 acc[4][4];
  zacc(acc);
  mfma128(As, Bsh, w, lane, acc);
  int q = lane >> 4, cl = lane & 15, wm = w >> 1, wn = w & 1;
  int rowb = blockIdx.x*128 + wm*64 + q*4;
  int colb = wn*64 + cl;
  #pragma unroll
  for (int m = 0; m < 4; m++)
    #pragma unroll
    for (int n = 0; n < 4; n++)
      #pragma unroll
      for (int r = 0; r < 4; r++){
        int row = rowb + m*16 + r, col = colb + n*16;
        if (row < NN){
          float v = fmaxf(acc[m][n][r] + gb[l*128 + col], 0.f);
          H[((size_t)(lg*NN + row))*512 + l*128 + col] = f2bf(v);
        }
      }
}

// ---------------- GEMM2: feats[coff+row][128] = H[12000][512] @ Wstc^T (f32) ----------------
__global__ __launch_bounds__(256) void k_gemm2(const ushort* __restrict__ A,
    const ushort* __restrict__ B, float* __restrict__ feats, int coff){
  __shared__ ushort As[16384];
  __shared__ ushort Bsh[16384];
  int tid = threadIdx.x, w = tid >> 6, lane = tid & 63;
  f32x4 acc[4][4];
  zacc(acc);
  #pragma unroll
  for (int kc = 0; kc < 4; kc++){
    if (kc) __syncthreads();
    stage128s(A + (size_t)blockIdx.x*128*512 + kc*128, 512, As, w, lane);
    stage128s(B + kc*128, 512, Bsh, w, lane);
    __syncthreads();
    mfma128(As, Bsh, w, lane, acc);
  }
  int q = lane >> 4, cl = lane & 15, wm = w >> 1, wn = w & 1;
  int rowb = blockIdx.x*128 + wm*64 + q*4;
  int colb = wn*64 + cl;
  #pragma unroll
  for (int m = 0; m < 4; m++)
    #pragma unroll
    for (int n = 0; n < 4; n++)
      #pragma unroll
      for (int r = 0; r < 4; r++){
        int row = rowb + m*16 + r;
        if (row < 2*NN)
          feats[(size_t)(coff + row)*128 + colb + n*16] = acc[m][n][r];
      }
}

__global__ void k_mean(const float* feats, float* out){
  int g = blockIdx.x / 48, ch = blockIdx.x - g*48;
  int c = threadIdx.x;
  float s = 0.f;
  int n0 = ch*125;
  for (int n = n0; n < n0 + 125; n++) s += feats[((size_t)(g*NN + n))*128 + c];
  atomicAdd(&out[g*128 + c], s * (1.0f/6000.0f));
}

// normalize rows -> fp8 e4m3, zero-pad to 6144 rows per graph
__global__ void k_xn(const float* feats, uchar* xn8){
  int lane = threadIdx.x;
  int rall = blockIdx.x*4 + threadIdx.y;   // 0..36863
  int g = rall / NP2, rl = rall - g*NP2;
  ushort* dst = (ushort*)(xn8 + ((size_t)(g*NP2 + rl))*128);
  if (rl < NN){
    const float2* src = (const float2*)&feats[((size_t)(g*NN + rl))*128];
    float2 v = src[lane];
    float ss = v.x*v.x + v.y*v.y;
    #pragma unroll
    for (int s = 32; s > 0; s >>= 1) ss += __shfl_xor(ss, s);
    float inv = 1.0f / fmaxf(sqrtf(ss), 1e-12f);
    int pk = __builtin_amdgcn_cvt_pk_fp8_f32(v.x*inv, v.y*inv, 0, false);
    dst[lane] = (ushort)(pk & 0xffff);
  } else {
    dst[lane] = 0;
  }
}

// ---------------- pairwise v13: MX-FP8 K=128, deg-5 economized poly, (256,3) ----------------
// Plateau-proven body: single bfr[4]+acc[4][4] MFMA region, no spill
// (WRITE ~333KB). Only delta vs v12: deg-7 -> deg-5 poly (see psumT).
__global__ __launch_bounds__(256, 3) void k_pair(const uchar* __restrict__ xn8,
                                                 float* Spart){
  __shared__ uchar Bs[2][8192];
  int bx = blockIdx.x;              // 2664 = 15*144 + 6*84
  int p, rt, c0, niter; bool diag;
  if (bx < 2160){
    int pp = bx / 144, rem = bx - pp*144;
    rt = rem / 6; int ch = rem - rt*6;
    p = c_nd[pp]; diag = false; c0 = ch*16; niter = 16;
  } else {
    int idd = bx - 2160;
    int pd = idd / 84, rem = idd - pd*84;
    int r_ = 0;
    while (c_dcum[r_ + 1] <= rem) r_++;
    rt = r_;
    int ch = rem - c_dcum[rt];
    p = c_dg[pd]; diag = true;
    c0 = 4*rt + ch*16;
    int left = 96 - c0;
    niter = left < 16 ? left : 16;
  }
  int i1 = c_i1[p], i2 = c_i2[p];
  int tid = threadIdx.x, w = tid >> 6, lane = tid & 63;
  int q = lane >> 4, cl = lane & 15;
  // A: 64 rows/wave = 4 m-tiles of 16; lane holds row (cl), k-bytes q*32..+32
  const uchar* Arow = xn8 + ((size_t)i1*NP2 + rt*256 + w*64 + cl)*128 + q*32;
  int8v afr[4];
  #pragma unroll
  for (int m = 0; m < 4; m++){
    uint4 lo = *(const uint4*)(Arow + m*2048);
    uint4 hi = *(const uint4*)(Arow + m*2048 + 16);
    afr[m] = (int8v){(int)lo.x,(int)lo.y,(int)lo.z,(int)lo.w,
                     (int)hi.x,(int)hi.y,(int)hi.z,(int)hi.w};
  }
  // LDS read byte-bases (swizzled), loop-invariant:
  int b0 = cl*128 + (((q*2  ) ^ (cl & 7)) << 4);
  int b1 = cl*128 + (((q*2+1) ^ (cl & 7)) << 4);
  const uchar* Bbase = xn8 + (size_t)i2*NP2*128;
  stage8(Bbase + (size_t)c0*8192, Bs[0], w, lane);
  f32x2 totw = {0.f, 0.f};
  const f32x4 z4 = {0.f,0.f,0.f,0.f};
  for (int it = 0; it < niter; it++){
    int cur = it & 1;
    __syncthreads();                               // drains staging of Bs[cur]
    if (it + 1 < niter)
      stage8(Bbase + (size_t)(c0+it+1)*8192, Bs[1-cur], w, lane);
    __builtin_amdgcn_s_setprio(1);
    int8v bfr[4];
    #pragma unroll
    for (int n = 0; n < 4; n++){
      uint4 lo = *(const uint4*)&Bs[cur][b0 + n*2048];
      uint4 hi = *(const uint4*)&Bs[cur][b1 + n*2048];
      bfr[n] = (int8v){(int)lo.x,(int)lo.y,(int)lo.z,(int)lo.w,
                       (int)hi.x,(int)hi.y,(int)hi.z,(int)hi.w};
    }
    f32x4 acc[4][4];
    #pragma unroll
    for (int m = 0; m < 4; m++)
      #pragma unroll
      for (int n = 0; n < 4; n++)
        acc[m][n] = __builtin_amdgcn_mfma_scale_f32_16x16x128_f8f6f4(
            afr[m], bfr[n], z4, 0, 0, 0, 0x7F, 0, 0x7F);
    __builtin_amdgcn_s_setprio(0);
    f32x2 t2 = psumT(acc);
    float wgt = (diag && (c0 + it) >= 4*rt + 4) ? 2.f : 1.f;
    totw = t2*wgt + totw;
  }
  float tot = totw.x + totw.y;
  #pragma unroll
  for (int s = 32; s > 0; s >>= 1) tot += __shfl_xor(tot, s);
  if (lane == 0) atomicAdd(&Spart[p*64 + (bx & 63)], tot);
}

__global__ void k_final(const float* Spart, float* out){
  int t = threadIdx.x;
  if (t < 21){
    float s = 0.f;
    for (int j = 0; j < 64; j++) s += Spart[t*64 + j];
    float v = s * (1.0f/360000000.0f);
    int i1 = c_i1[t], i2 = c_i2[t];
    out[768 + i1*6 + i2] = v;
    out[768 + i2*6 + i1] = v;
  }
}

extern "C" void kernel_launch(void* const* d_in, const int* in_sizes, int n_in,
                              void* d_out, int out_size, void* d_ws, size_t ws_size,
                              hipStream_t stream){
  (void)in_sizes; (void)n_in; (void)out_size; (void)ws_size;
  const float* x   = (const float*)d_in[0];
  const int*   ei  = (const int*)d_in[1];
  const float* ea  = (const float*)d_in[2];
  const float* gW  = (const float*)d_in[3];
  const float* gb  = (const float*)d_in[4];
  const float* Wsm = (const float*)d_in[5];
  float* out = (float*)d_out;
  char* ws = (char*)d_ws;
  // workspace (bytes), peak ~52.0 MiB
  float*  feats  = (float*) (ws + 0);           // 18,432,000
  int*    counts = (int*)   (ws + 18432000);    //    144,000
  int*    offs   = (int*)   (ws + 18576000);    //    144,000
  int*    cursor = (int*)   (ws + 18720000);    //    144,000
  float*  Spart  = (float*) (ws + 18864000);    //      8,192   [zero 18,432,000..18,872,192)
  float4* dis4   = (float4*)(ws + 18872192);    //    576,000
  int2*   elist2 = (int2*)  (ws + 19448192);    //  4,608,000
  ushort* Wtc    = (ushort*)(ws + 24056192);    //    131,072
  ushort* Wstc   = (ushort*)(ws + 24187264);    //    131,072
  ushort* xbf    = (ushort*)(ws + 24318336);    //  3,072,000
  ushort* agg    = (ushort*)(ws + 27394560);    // 12,288,000 (+8 KB pad)
  ushort* H      = (ushort*)(ws + 39690752);    // 12,320,768 (12032 rows) -> end 52,011,520
  uchar*  xn8    = (uchar*) (ws + 24318336);    //  4,718,592 overlay (xbf/agg dead by k_xn)

  k_init <<<dim3(256),  dim3(256), 0, stream>>>(gW, Wsm, Wtc, Wstc,
                                                (float4*)(ws + 18432000), out);
  k_count<<<dim3(2250), dim3(256), 0, stream>>>(ei, counts);
  k_scan <<<dim3(6),    dim3(256), 0, stream>>>(counts, offs, cursor);
  k_place<<<dim3(2250), dim3(256), 0, stream>>>(ei, cursor, elist2);
  k_deg  <<<dim3(141),  dim3(256), 0, stream>>>(ea, offs, counts, elist2, dis4);
  for (int c = 0; c < 3; c++){
    k_cvtx   <<<dim3(1500), dim3(256), 0, stream>>>(
        (const float4*)(x + (size_t)c*2*NN*128), (uint2*)xbf, 384000);
    k_gather1<<<dim3(3000), dim3(64,4), 0, stream>>>(ea, dis4, offs, counts, elist2,
                                                     xbf, agg, c);
    k_gemm1b <<<dim3(47,8), dim3(256), 0, stream>>>(agg, Wtc, gb, H);
    k_gemm2  <<<dim3(94),   dim3(256), 0, stream>>>(H, Wstc, feats, c*2*NN);
  }
  k_mean <<<dim3(288),  dim3(128),  0, stream>>>(feats, out);
  k_xn   <<<dim3(9216), dim3(64,4), 0, stream>>>(feats, xn8);
  k_pair <<<dim3(2664), dim3(256),  0, stream>>>(xn8, Spart);
  k_final<<<dim3(1),    dim3(64),   0, stream>>>(Spart, out);
}

// Round 15
// 436.871 us; speedup vs baseline: 1.2372x; 1.0265x over previous
//
#include <hip/hip_runtime.h>

#define NG 6
#define NN 6000
#define NE 96000
#define NP2 6144   // 24*256, padded rows per graph for k_pair

typedef unsigned int uint;
typedef unsigned short ushort;
typedef unsigned char uchar;
typedef __attribute__((ext_vector_type(8))) short short8;
typedef __attribute__((ext_vector_type(8))) int int8v;
typedef __attribute__((ext_vector_type(4))) float f32x4;
typedef __attribute__((ext_vector_type(2))) float f32x2;

__device__ __forceinline__ ushort f2bf(float f){
  uint u = __float_as_uint(f);
  u = (u + 0x7fffu + ((u >> 16) & 1u)) >> 16;
  return (ushort)u;
}
__device__ __forceinline__ float bf2f(uint u){ return __uint_as_float(u << 16); }

__device__ __forceinline__ void async16(const void* g, void* l){
  __builtin_amdgcn_global_load_lds(
      (const __attribute__((address_space(1))) unsigned int*)g,
      (__attribute__((address_space(3))) unsigned int*)l, 16, 0, 0);
}

__device__ __constant__ int c_i1[21] = {0,0,0,0,0,0,1,1,1,1,1,2,2,2,2,3,3,3,4,4,5};
__device__ __constant__ int c_i2[21] = {0,1,2,3,4,5,1,2,3,4,5,2,3,4,5,3,4,5,4,5,5};
// non-diag pair ids (15) and diag pair ids (6)
__device__ __constant__ int c_nd[15] = {1,2,3,4,5,7,8,9,10,12,13,14,16,17,19};
__device__ __constant__ int c_dg[6]  = {0,6,11,15,18,20};
// cumulative chunk counts per diag row-tile rt=0..23, chunk=16 col-tiles
__device__ __constant__ int c_dcum[25] = {0,6,12,18,24,29,34,39,44,48,52,56,60,
                                          63,66,69,72,74,76,78,80,81,82,83,84};

// ---------------- MFMA tile helpers (XOR-swizzled LDS, bf16 GEMMs) ----------------
// LDS row r (256B): chunk c at slot c^(r&15).
__device__ __forceinline__ void stage128s(const ushort* __restrict__ gsrc, int stride,
                                          ushort* lds, int w, int lane){
  #pragma unroll
  for (int i = 0; i < 8; i++){
    int off = (w*8 + i) * 512;
    int rowi = (w*8 + i)*4 + (lane >> 4);
    int chunk = (lane & 15) ^ (rowi & 15);
    async16(gsrc + (size_t)rowi*stride + chunk*8, (void*)&lds[off]);
  }
}

// stage a 64-row x 128-byte fp8 tile (8KB): row r (128B = 8 slots of 16B),
// source chunk (slot^(r&7)) lands in slot -> read with same XOR is identity.
__device__ __forceinline__ void stage8(const uchar* __restrict__ gsrc,
                                       uchar* lds, int w, int lane){
  #pragma unroll
  for (int j = 0; j < 2; j++){
    int cj = w*2 + j;
    int d = cj*64 + lane;           // 16B-chunk index 0..511
    int row = d >> 3, slot = d & 7;
    async16(gsrc + (size_t)row*128 + ((slot ^ (row & 7)) << 4),
            (void*)(lds + cj*1024));
  }
}

__device__ __forceinline__ void mfma128(const ushort* As, const ushort* Bs,
                                        int w, int lane, f32x4 acc[4][4]){
  int q = lane >> 4, cl = lane & 15;
  int wm = w >> 1, wn = w & 1;
  #pragma unroll
  for (int ks = 0; ks < 4; ks++){
    short8 af[4], bfr[4];
    int ch = ((ks*4 + q) ^ cl) * 8;
    #pragma unroll
    for (int m = 0; m < 4; m++) af[m]  = *(const short8*)&As[(wm*64 + m*16 + cl)*128 + ch];
    #pragma unroll
    for (int n = 0; n < 4; n++) bfr[n] = *(const short8*)&Bs[(wn*64 + n*16 + cl)*128 + ch];
    #pragma unroll
    for (int m = 0; m < 4; m++)
      #pragma unroll
      for (int n = 0; n < 4; n++)
        acc[m][n] = __builtin_amdgcn_mfma_f32_16x16x32_bf16(af[m], bfr[n], acc[m][n], 0, 0, 0);
  }
}
__device__ __forceinline__ void zacc(f32x4 acc[4][4]){
  #pragma unroll
  for (int m = 0; m < 4; m++)
    #pragma unroll
    for (int n = 0; n < 4; n++) acc[m][n] = (f32x4){0.f,0.f,0.f,0.f};
}

// odd poly: P(d) ~ 10.5*tanh(d) on [-1,1].
// deg-3 via three-step Chebyshev economization of the proven deg-9:
//   deg-9 -> deg-7 (err 3.3e-4 P-units) -> deg-5 (+4.0e-3) -> drop T5 of d^5:
//   d^5 ~ (20d^3 - 5d)/16, added err |TE5|/16 = 4.7e-2 P-units worst-case
//   -> <= 4.7e-3 per sim entry after /360e6 norm even with full coherence
//   (T5 oscillation averages it far lower in practice); stacked total ~5.5e-3,
//   2.7x under the 1.5e-2 threshold. P3(1)=7.953 vs 10.5tanh(1)=7.996.
// 6 scalar VALU instrs per f32x2 group (was 8 deg-5, 10 deg-7, 12 deg-9).
#define TF1 10.23127844f
#define TF3 (-2.27827312f)
__device__ __forceinline__ f32x2 psumT(const f32x4 acc[4][4]){
  f32x2 t2 = {0.f, 0.f};
  #pragma unroll
  for (int m = 0; m < 4; m++)
    #pragma unroll
    for (int n = 0; n < 4; n++)
      #pragma unroll
      for (int rp = 0; rp < 2; rp++){
        f32x2 d = { acc[m][n][rp*2], acc[m][n][rp*2+1] };
        f32x2 t = d*d;
        f32x2 qq = t*TF3 + TF1;
        t2 = d*qq + t2;
      }
  return t2;
}

// ---------------- init: zero scratch/out + convert weights (3 launches -> 1) ----------------
// Wtc[l][c][k] = W[l][k][c];  Wstc[n][l*128+c'] = Ws[l][c'][n]
__global__ void k_init(const float* W, const float* Wsm, ushort* Wtc, ushort* Wstc,
                       float4* zr, float* out){
  int i = blockIdx.x*256 + threadIdx.x;   // 65536
  int l = i >> 14, rem = i & 16383;
  int a = rem >> 7, b = rem & 127;        // W: a=k,b=c ; Ws: a=c',b=n
  Wtc[(l << 14) + b*128 + a] = f2bf(W[i]);
  Wstc[b*512 + l*128 + a]    = f2bf(Wsm[i]);
  if (i < 27512) zr[i] = make_float4(0.f,0.f,0.f,0.f);
  if (i < 804)   out[i] = 0.f;
}

__global__ void k_count(const int* ei, int* counts){
  int i = blockIdx.x*256 + threadIdx.x;
  if (i >= NG*NE) return;
  int g = i / NE, e = i - g*NE;
  atomicAdd(&counts[g*NN + ei[g*2*NE + NE + e]], 1);
}
__global__ void k_scan(const int* counts, int* offs, int* cursor){
  __shared__ int sm[256];
  int g = blockIdx.x, t = threadIdx.x;
  const int* c = counts + g*NN;
  int i0 = t*24, i1 = i0 + 24; if (i1 > NN) i1 = NN; if (i0 > NN) i0 = NN;
  int s = 0;
  for (int i = i0; i < i1; i++) s += c[i];
  sm[t] = s;
  __syncthreads();
  for (int off = 1; off < 256; off <<= 1){
    int v = (t >= off) ? sm[t - off] : 0;
    __syncthreads();
    sm[t] += v;
    __syncthreads();
  }
  int run = sm[t] - s;
  for (int i = i0; i < i1; i++){
    offs[g*NN + i] = run; cursor[g*NN + i] = run; run += c[i];
  }
}
__global__ void k_place(const int* ei, int* cursor, int2* elist2){
  int i = blockIdx.x*256 + threadIdx.x;
  if (i >= NG*NE) return;
  int g = i / NE, e = i - g*NE;
  int col = ei[g*2*NE + NE + e];
  int row = ei[g*2*NE + e];
  int pos = atomicAdd(&cursor[g*NN + col], 1);
  elist2[g*NE + pos] = make_int2(e, row);
}
__global__ void k_deg(const float* __restrict__ ea, const int* __restrict__ offs,
                      const int* __restrict__ counts, const int2* __restrict__ elist2,
                      float4* __restrict__ dis4){
  int i = blockIdx.x*256 + threadIdx.x;
  if (i >= NG*NN) return;
  int g = i / NN;
  int beg = offs[i], cnt = counts[i];
  const int2* el = elist2 + (size_t)g*NE;
  const float* eag = ea + (size_t)g*NE*6;
  float4 s = make_float4(1.f,1.f,1.f,1.f);
  for (int j = 0; j < cnt; j++){
    int e = el[beg + j].x;
    float2 wa = *(const float2*)(eag + (size_t)e*6 + 2);
    float2 wb = *(const float2*)(eag + (size_t)e*6 + 4);
    s.x += wa.x; s.y += wa.y; s.z += wb.x; s.w += wb.y;
  }
  dis4[i] = make_float4(rsqrtf(fmaxf(s.x,1e-30f)), rsqrtf(fmaxf(s.y,1e-30f)),
                        rsqrtf(fmaxf(s.z,1e-30f)), rsqrtf(fmaxf(s.w,1e-30f)));
}

__global__ void k_cvtx(const float4* x, uint2* xbf, int n4){
  int i = blockIdx.x*256 + threadIdx.x;
  if (i >= n4) return;
  float4 v = x[i];
  xbf[i] = make_uint2((uint)f2bf(v.x) | ((uint)f2bf(v.y) << 16),
                      (uint)f2bf(v.z) | ((uint)f2bf(v.w) << 16));
}

// ---------------- aggregate-first: agg[lg*4+l][n][128] = dn_l*(sum coef*x[r] + dn_l*x[n]) ----------------
__global__ __launch_bounds__(256) void k_gather1(const float* __restrict__ ea,
    const float4* __restrict__ dis4, const int* __restrict__ offs,
    const int* __restrict__ counts, const int2* __restrict__ elist2,
    const ushort* __restrict__ xbf, ushort* __restrict__ agg, int c){
  __shared__ int    sr[4][64];
  __shared__ float4 sc[4][64];
  int lane = threadIdx.x, wy = threadIdx.y;
  int nidx = blockIdx.x*4 + wy;            // 0..11999
  int lg = nidx / NN, n = nidx - lg*NN;
  int g = c*2 + lg;
  float4 dn4 = dis4[g*NN + n];
  const uint* xrow = (const uint*)xbf + (size_t)lg*NN*64;
  uint xv = xrow[(size_t)n*64 + lane];
  f32x2 xs = {bf2f(xv & 0xffffu), bf2f(xv >> 16)};
  f32x2 a0 = xs*dn4.x, a1 = xs*dn4.y, a2 = xs*dn4.z, a3 = xs*dn4.w;
  int beg = offs[g*NN + n], cnt = counts[g*NN + n];
  const int2*  el  = elist2 + (size_t)g*NE;
  const float* eag = ea + (size_t)g*NE*6;
  for (int j0 = 0; j0 < cnt; j0 += 64){
    int take = cnt - j0; if (take > 64) take = 64;
    if (lane < take){
      int2 er = el[beg + j0 + lane];
      float2 wa = *(const float2*)(eag + (size_t)er.x*6 + 2);
      float2 wb = *(const float2*)(eag + (size_t)er.x*6 + 4);
      float4 dr = dis4[g*NN + er.y];
      sr[wy][lane] = er.y;
      sc[wy][lane] = make_float4(wa.x*dr.x, wa.y*dr.y, wb.x*dr.z, wb.y*dr.w);
    }
    int j = 0;
    for (; j + 4 <= take; j += 4){
      int r0 = sr[wy][j], r1 = sr[wy][j+1], r2 = sr[wy][j+2], r3 = sr[wy][j+3];
      float4 c0 = sc[wy][j], c1 = sc[wy][j+1], c2 = sc[wy][j+2], c3 = sc[wy][j+3];
      uint x0 = xrow[(size_t)r0*64 + lane];
      uint x1 = xrow[(size_t)r1*64 + lane];
      uint x2 = xrow[(size_t)r2*64 + lane];
      uint x3 = xrow[(size_t)r3*64 + lane];
      f32x2 v;
      v = (f32x2){bf2f(x0 & 0xffffu), bf2f(x0 >> 16)};
      a0 = v*c0.x + a0; a1 = v*c0.y + a1; a2 = v*c0.z + a2; a3 = v*c0.w + a3;
      v = (f32x2){bf2f(x1 & 0xffffu), bf2f(x1 >> 16)};
      a0 = v*c1.x + a0; a1 = v*c1.y + a1; a2 = v*c1.z + a2; a3 = v*c1.w + a3;
      v = (f32x2){bf2f(x2 & 0xffffu), bf2f(x2 >> 16)};
      a0 = v*c2.x + a0; a1 = v*c2.y + a1; a2 = v*c2.z + a2; a3 = v*c2.w + a3;
      v = (f32x2){bf2f(x3 & 0xffffu), bf2f(x3 >> 16)};
      a0 = v*c3.x + a0; a1 = v*c3.y + a1; a2 = v*c3.z + a2; a3 = v*c3.w + a3;
    }
    for (; j < take; j++){
      int r0 = sr[wy][j];
      float4 c0 = sc[wy][j];
      uint x0 = xrow[(size_t)r0*64 + lane];
      f32x2 v = (f32x2){bf2f(x0 & 0xffffu), bf2f(x0 >> 16)};
      a0 = v*c0.x + a0; a1 = v*c0.y + a1; a2 = v*c0.z + a2; a3 = v*c0.w + a3;
    }
  }
  a0 = a0*dn4.x; a1 = a1*dn4.y; a2 = a2*dn4.z; a3 = a3*dn4.w;
  uint* ag = (uint*)agg;
  ag[((size_t)((lg*4+0)*NN + n))*64 + lane] = (uint)f2bf(a0.x) | ((uint)f2bf(a0.y) << 16);
  ag[((size_t)((lg*4+1)*NN + n))*64 + lane] = (uint)f2bf(a1.x) | ((uint)f2bf(a1.y) << 16);
  ag[((size_t)((lg*4+2)*NN + n))*64 + lane] = (uint)f2bf(a2.x) | ((uint)f2bf(a2.y) << 16);
  ag[((size_t)((lg*4+3)*NN + n))*64 + lane] = (uint)f2bf(a3.x) | ((uint)f2bf(a3.y) << 16);
}

// ---------------- GEMM1: H[lg*NN+row][l*128+col] = relu(agg_l @ W_l + b_l)  (bf16) ----------------
// (R11's fused k_gemmf regressed +70us: only 94 blocks on 256 CUs. Separate
// kernels keep gemm1b at 376 blocks; the H round-trip is the cheaper evil.)
__global__ __launch_bounds__(256) void k_gemm1b(const ushort* __restrict__ agg,
    const ushort* __restrict__ Wtc, const float* __restrict__ gb,
    ushort* __restrict__ H){
  __shared__ ushort As[16384];
  __shared__ ushort Bsh[16384];
  int by = blockIdx.y;            // lg*4 + l
  int lg = by >> 2, l = by & 3;
  int tid = threadIdx.x, w = tid >> 6, lane = tid & 63;
  stage128s(agg + (size_t)by*NN*128 + (size_t)blockIdx.x*16384, 128, As, w, lane);
  stage128s(Wtc + (l << 14), 128, Bsh, w, lane);
  __syncthreads();
  f32x4 acc[4][4];
  zacc(acc);
  mfma128(As, Bsh, w, lane, acc);
  int q = lane >> 4, cl = lane & 15, wm = w >> 1, wn = w & 1;
  int rowb = blockIdx.x*128 + wm*64 + q*4;
  int colb = wn*64 + cl;
  #pragma unroll
  for (int m = 0; m < 4; m++)
    #pragma unroll
    for (int n = 0; n < 4; n++)
      #pragma unroll
      for (int r = 0; r < 4; r++){
        int row = rowb + m*16 + r, col = colb + n*16;
        if (row < NN){
          float v = fmaxf(acc[m][n][r] + gb[l*128 + col], 0.f);
          H[((size_t)(lg*NN + row))*512 + l*128 + col] = f2bf(v);
        }
      }
}

// ---------------- GEMM2: feats[coff+row][128] = H[12000][512] @ Wstc^T (f32) ----------------
__global__ __launch_bounds__(256) void k_gemm2(const ushort* __restrict__ A,
    const ushort* __restrict__ B, float* __restrict__ feats, int coff){
  __shared__ ushort As[16384];
  __shared__ ushort Bsh[16384];
  int tid = threadIdx.x, w = tid >> 6, lane = tid & 63;
  f32x4 acc[4][4];
  zacc(acc);
  #pragma unroll
  for (int kc = 0; kc < 4; kc++){
    if (kc) __syncthreads();
    stage128s(A + (size_t)blockIdx.x*128*512 + kc*128, 512, As, w, lane);
    stage128s(B + kc*128, 512, Bsh, w, lane);
    __syncthreads();
    mfma128(As, Bsh, w, lane, acc);
  }
  int q = lane >> 4, cl = lane & 15, wm = w >> 1, wn = w & 1;
  int rowb = blockIdx.x*128 + wm*64 + q*4;
  int colb = wn*64 + cl;
  #pragma unroll
  for (int m = 0; m < 4; m++)
    #pragma unroll
    for (int n = 0; n < 4; n++)
      #pragma unroll
      for (int r = 0; r < 4; r++){
        int row = rowb + m*16 + r;
        if (row < 2*NN)
          feats[(size_t)(coff + row)*128 + colb + n*16] = acc[m][n][r];
      }
}

__global__ void k_mean(const float* feats, float* out){
  int g = blockIdx.x / 48, ch = blockIdx.x - g*48;
  int c = threadIdx.x;
  float s = 0.f;
  int n0 = ch*125;
  for (int n = n0; n < n0 + 125; n++) s += feats[((size_t)(g*NN + n))*128 + c];
  atomicAdd(&out[g*128 + c], s * (1.0f/6000.0f));
}

// normalize rows -> fp8 e4m3, zero-pad to 6144 rows per graph
__global__ void k_xn(const float* feats, uchar* xn8){
  int lane = threadIdx.x;
  int rall = blockIdx.x*4 + threadIdx.y;   // 0..36863
  int g = rall / NP2, rl = rall - g*NP2;
  ushort* dst = (ushort*)(xn8 + ((size_t)(g*NP2 + rl))*128);
  if (rl < NN){
    const float2* src = (const float2*)&feats[((size_t)(g*NN + rl))*128];
    float2 v = src[lane];
    float ss = v.x*v.x + v.y*v.y;
    #pragma unroll
    for (int s = 32; s > 0; s >>= 1) ss += __shfl_xor(ss, s);
    float inv = 1.0f / fmaxf(sqrtf(ss), 1e-12f);
    int pk = __builtin_amdgcn_cvt_pk_fp8_f32(v.x*inv, v.y*inv, 0, false);
    dst[lane] = (ushort)(pk & 0xffff);
  } else {
    dst[lane] = 0;
  }
}

// ---------------- pairwise v14: MX-FP8 K=128, deg-3 economized poly, (256,3) ----------------
// Plateau-proven body: single bfr[4]+acc[4][4] MFMA region, no spill
// (WRITE ~333KB). Only delta vs v13: deg-5 -> deg-3 poly (see psumT).
__global__ __launch_bounds__(256, 3) void k_pair(const uchar* __restrict__ xn8,
                                                 float* Spart){
  __shared__ uchar Bs[2][8192];
  int bx = blockIdx.x;              // 2664 = 15*144 + 6*84
  int p, rt, c0, niter; bool diag;
  if (bx < 2160){
    int pp = bx / 144, rem = bx - pp*144;
    rt = rem / 6; int ch = rem - rt*6;
    p = c_nd[pp]; diag = false; c0 = ch*16; niter = 16;
  } else {
    int idd = bx - 2160;
    int pd = idd / 84, rem = idd - pd*84;
    int r_ = 0;
    while (c_dcum[r_ + 1] <= rem) r_++;
    rt = r_;
    int ch = rem - c_dcum[rt];
    p = c_dg[pd]; diag = true;
    c0 = 4*rt + ch*16;
    int left = 96 - c0;
    niter = left < 16 ? left : 16;
  }
  int i1 = c_i1[p], i2 = c_i2[p];
  int tid = threadIdx.x, w = tid >> 6, lane = tid & 63;
  int q = lane >> 4, cl = lane & 15;
  // A: 64 rows/wave = 4 m-tiles of 16; lane holds row (cl), k-bytes q*32..+32
  const uchar* Arow = xn8 + ((size_t)i1*NP2 + rt*256 + w*64 + cl)*128 + q*32;
  int8v afr[4];
  #pragma unroll
  for (int m = 0; m < 4; m++){
    uint4 lo = *(const uint4*)(Arow + m*2048);
    uint4 hi = *(const uint4*)(Arow + m*2048 + 16);
    afr[m] = (int8v){(int)lo.x,(int)lo.y,(int)lo.z,(int)lo.w,
                     (int)hi.x,(int)hi.y,(int)hi.z,(int)hi.w};
  }
  // LDS read byte-bases (swizzled), loop-invariant:
  int b0 = cl*128 + (((q*2  ) ^ (cl & 7)) << 4);
  int b1 = cl*128 + (((q*2+1) ^ (cl & 7)) << 4);
  const uchar* Bbase = xn8 + (size_t)i2*NP2*128;
  stage8(Bbase + (size_t)c0*8192, Bs[0], w, lane);
  f32x2 totw = {0.f, 0.f};
  const f32x4 z4 = {0.f,0.f,0.f,0.f};
  for (int it = 0; it < niter; it++){
    int cur = it & 1;
    __syncthreads();                               // drains staging of Bs[cur]
    if (it + 1 < niter)
      stage8(Bbase + (size_t)(c0+it+1)*8192, Bs[1-cur], w, lane);
    __builtin_amdgcn_s_setprio(1);
    int8v bfr[4];
    #pragma unroll
    for (int n = 0; n < 4; n++){
      uint4 lo = *(const uint4*)&Bs[cur][b0 + n*2048];
      uint4 hi = *(const uint4*)&Bs[cur][b1 + n*2048];
      bfr[n] = (int8v){(int)lo.x,(int)lo.y,(int)lo.z,(int)lo.w,
                       (int)hi.x,(int)hi.y,(int)hi.z,(int)hi.w};
    }
    f32x4 acc[4][4];
    #pragma unroll
    for (int m = 0; m < 4; m++)
      #pragma unroll
      for (int n = 0; n < 4; n++)
        acc[m][n] = __builtin_amdgcn_mfma_scale_f32_16x16x128_f8f6f4(
            afr[m], bfr[n], z4, 0, 0, 0, 0x7F, 0, 0x7F);
    __builtin_amdgcn_s_setprio(0);
    f32x2 t2 = psumT(acc);
    float wgt = (diag && (c0 + it) >= 4*rt + 4) ? 2.f : 1.f;
    totw = t2*wgt + totw;
  }
  float tot = totw.x + totw.y;
  #pragma unroll
  for (int s = 32; s > 0; s >>= 1) tot += __shfl_xor(tot, s);
  if (lane == 0) atomicAdd(&Spart[p*64 + (bx & 63)], tot);
}

__global__ void k_final(const float* Spart, float* out){
  int t = threadIdx.x;
  if (t < 21){
    float s = 0.f;
    for (int j = 0; j < 64; j++) s += Spart[t*64 + j];
    float v = s * (1.0f/360000000.0f);
    int i1 = c_i1[t], i2 = c_i2[t];
    out[768 + i1*6 + i2] = v;
    out[768 + i2*6 + i1] = v;
  }
}

extern "C" void kernel_launch(void* const* d_in, const int* in_sizes, int n_in,
                              void* d_out, int out_size, void* d_ws, size_t ws_size,
                              hipStream_t stream){
  (void)in_sizes; (void)n_in; (void)out_size; (void)ws_size;
  const float* x   = (const float*)d_in[0];
  const int*   ei  = (const int*)d_in[1];
  const float* ea  = (const float*)d_in[2];
  const float* gW  = (const float*)d_in[3];
  const float* gb  = (const float*)d_in[4];
  const float* Wsm = (const float*)d_in[5];
  float* out = (float*)d_out;
  char* ws = (char*)d_ws;
  // workspace (bytes), peak ~52.0 MiB
  float*  feats  = (float*) (ws + 0);           // 18,432,000
  int*    counts = (int*)   (ws + 18432000);    //    144,000
  int*    offs   = (int*)   (ws + 18576000);    //    144,000
  int*    cursor = (int*)   (ws + 18720000);    //    144,000
  float*  Spart  = (float*) (ws + 18864000);    //      8,192   [zero 18,432,000..18,872,192)
  float4* dis4   = (float4*)(ws + 18872192);    //    576,000
  int2*   elist2 = (int2*)  (ws + 19448192);    //  4,608,000
  ushort* Wtc    = (ushort*)(ws + 24056192);    //    131,072
  ushort* Wstc   = (ushort*)(ws + 24187264);    //    131,072
  ushort* xbf    = (ushort*)(ws + 24318336);    //  3,072,000
  ushort* agg    = (ushort*)(ws + 27394560);    // 12,288,000 (+8 KB pad)
  ushort* H      = (ushort*)(ws + 39690752);    // 12,320,768 (12032 rows) -> end 52,011,520
  uchar*  xn8    = (uchar*) (ws + 24318336);    //  4,718,592 overlay (xbf/agg dead by k_xn)

  k_init <<<dim3(256),  dim3(256), 0, stream>>>(gW, Wsm, Wtc, Wstc,
                                                (float4*)(ws + 18432000), out);
  k_count<<<dim3(2250), dim3(256), 0, stream>>>(ei, counts);
  k_scan <<<dim3(6),    dim3(256), 0, stream>>>(counts, offs, cursor);
  k_place<<<dim3(2250), dim3(256), 0, stream>>>(ei, cursor, elist2);
  k_deg  <<<dim3(141),  dim3(256), 0, stream>>>(ea, offs, counts, elist2, dis4);
  for (int c = 0; c < 3; c++){
    k_cvtx   <<<dim3(1500), dim3(256), 0, stream>>>(
        (const float4*)(x + (size_t)c*2*NN*128), (uint2*)xbf, 384000);
    k_gather1<<<dim3(3000), dim3(64,4), 0, stream>>>(ea, dis4, offs, counts, elist2,
                                                     xbf, agg, c);
    k_gemm1b <<<dim3(47,8), dim3(256), 0, stream>>>(agg, Wtc, gb, H);
    k_gemm2  <<<dim3(94),   dim3(256), 0, stream>>>(H, Wstc, feats, c*2*NN);
  }
  k_mean <<<dim3(288),  dim3(128),  0, stream>>>(feats, out);
  k_xn   <<<dim3(9216), dim3(64,4), 0, stream>>>(feats, xn8);
  k_pair <<<dim3(2664), dim3(256),  0, stream>>>(xn8, Spart);
  k_final<<<dim3(1),    dim3(64),   0, stream>>>(Spart, out);
}